// Round 17
// baseline (2002.828 us; speedup 1.0000x reference)
//
#include <hip/hip_runtime.h>
#include <hip/hip_bf16.h>
#include <stdint.h>

typedef __bf16 bf16_t;
typedef __bf16 bf16x8 __attribute__((ext_vector_type(8)));
typedef __bf16 bf16x4 __attribute__((ext_vector_type(4)));
typedef float f32x4 __attribute__((ext_vector_type(4)));
typedef unsigned int u32;
typedef unsigned short u16;

static constexpr int Bd = 64, Sd = 512, Dd = 512, Hd = 8, Ld = 4, FFd = 2048, Zd = 64, FUTd = 96;

// ---------------- bijective XCD-aware block swizzle (T1, m204 form) ----------------
__device__ __forceinline__ int xcd_swz(int flat, int nwg) {
    int q = nwg >> 3, r = nwg & 7;
    int xcd = flat & 7, idx = flat >> 3;
    return (xcd < r ? xcd * (q + 1) : r * (q + 1) + (xcd - r) * q) + idx;
}

// ---------------- async global->LDS (16B per lane, wave-uniform LDS base) ----------------
__device__ __forceinline__ void gld_lds16(const bf16_t* g, bf16_t* l) {
    __builtin_amdgcn_global_load_lds(
        (const __attribute__((address_space(1))) u32*)g,
        (__attribute__((address_space(3))) u32*)l, 16, 0, 0);
}

// ---------------- fp32 -> bf16 conversion (vectorized x4) ----------------
__global__ void cvt_k(const float* __restrict__ in, bf16_t* __restrict__ out, int n4) {
    int i = blockIdx.x * 256 + threadIdx.x;
    if (i >= n4) return;
    float4 v = ((const float4*)in)[i];
    bf16x4 o;
    o[0] = (bf16_t)v.x; o[1] = (bf16_t)v.y; o[2] = (bf16_t)v.z; o[3] = (bf16_t)v.w;
    ((bf16x4*)out)[i] = o;
}

// ---------------- 256x256 8-phase-lite GEMM (qkv / ff1): C = A@W^T + bias [relu] ----------------
// 8 waves (2M x 4N), BK=64, 2x64KB LDS dbuf. Per K-tile, 4 phases:
//   { ds_read A-quadrant (+B once) ; lgkmcnt(0) ; barrier ; stage 1 half-tile of t+1
//     into OTHER buffer ; 16 MFMA }.
// Race-free: buf(t+1&1)'s last reader passed tile t-1's phase-3 barrier; staged loads
// drain at the tile-boundary vmcnt(0) after 1-4 MFMA phases of flight.
template<bool RELU>
__global__ __launch_bounds__(512, 2) void gemm256_k(
    const bf16_t* __restrict__ A, const bf16_t* __restrict__ W,
    const float* __restrict__ bias, bf16_t* __restrict__ outb,
    int M, int N, int K)
{
    __shared__ __align__(16) bf16_t sm[2][32768];   // [buf][A-lo|A-hi|B-lo|B-hi], 8192 each
    const int tid  = threadIdx.x;
    const int lane = tid & 63;
    const int wid  = tid >> 6;
    const int wm   = wid >> 2, wn = wid & 3;
    const int r15  = lane & 15;
    const int g4   = lane >> 4;

    const int nwg  = gridDim.x * gridDim.y;
    const int flat = xcd_swz(blockIdx.y * gridDim.x + blockIdx.x, nwg);
    const int bm   = (flat / gridDim.x) * 256;
    const int bn   = (flat % gridDim.x) * 256;

    // stage half-tile h (0=A-lo 1=A-hi 2=B-lo 3=B-hi) of K-tile at kt into buf b.
    // 1024 chunks; thread covers slots q=tid and q=tid+512; linear LDS dest
    // (wave-uniform base + lane*16B), global source inverse-swizzled (G21 both-sides).
    auto stage_half = [&](int b, int h, int kt) {
        const bf16_t* src = (h < 2) ? A : W;
        const int rbase = ((h < 2) ? bm : bn) + ((h & 1) << 7);
        bf16_t* dst = &sm[b][0] + h * 8192;
#pragma unroll
        for (int it = 0; it < 2; ++it) {
            const int q = it * 512 + tid;
            const int r = q >> 3, c = q & 7;
            const int cl = c ^ (r & 7);
            gld_lds16(src + (size_t)(rbase + r) * K + kt + cl * 8,
                      dst + (it * 512 + wid * 64) * 8);   // HW adds lane*16B
        }
    };

    f32x4 acc[8][4];
#pragma unroll
    for (int i = 0; i < 8; ++i)
#pragma unroll
        for (int n = 0; n < 4; ++n) acc[i][n] = (f32x4){0.f, 0.f, 0.f, 0.f};

    const int NT = K >> 6;
#pragma unroll
    for (int h = 0; h < 4; ++h) stage_half(0, h, 0);
    __syncthreads();                        // prologue: full drain, tile 0 visible

    bf16x8 bfr[4][2];
    for (int t = 0; t < NT; ++t) {
        const int cur = t & 1;
        const bf16_t* Ah = &sm[cur][0] + wm * 8192;                  // this wave's A half
        const bf16_t* Bh = &sm[cur][0] + 16384 + (wn >> 1) * 8192;   // this wave's B half
        const int ktn = (t + 1) << 6;
        const bool pf = (t + 1 < NT);
#pragma unroll
        for (int p = 0; p < 4; ++p) {
            if (p == 0) {
#pragma unroll
                for (int n = 0; n < 4; ++n)
#pragma unroll
                    for (int kk = 0; kk < 2; ++kk) {
                        const int rl = (wn & 1) * 64 + n * 16 + r15;
                        const int c = (kk * 4 + g4) ^ (rl & 7);
                        bfr[n][kk] = *(const bf16x8*)(Bh + rl * 64 + c * 8);
                    }
            }
            bf16x8 af[2][2];
#pragma unroll
            for (int ii = 0; ii < 2; ++ii)
#pragma unroll
                for (int kk = 0; kk < 2; ++kk) {
                    const int rl = (p * 2 + ii) * 16 + r15;
                    const int c = (kk * 4 + g4) ^ (rl & 7);
                    af[ii][kk] = *(const bf16x8*)(Ah + rl * 64 + c * 8);
                }
            asm volatile("s_waitcnt lgkmcnt(0)" ::: "memory");  // own ds_reads complete
            __builtin_amdgcn_s_barrier();                       // all waves' reads complete
            __builtin_amdgcn_sched_barrier(0);
            if (pf) stage_half(cur ^ 1, p, ktn);                // other buffer: provably idle
            __builtin_amdgcn_s_setprio(1);
#pragma unroll
            for (int ii = 0; ii < 2; ++ii)
#pragma unroll
                for (int n = 0; n < 4; ++n)
#pragma unroll
                    for (int kk = 0; kk < 2; ++kk)
                        acc[p * 2 + ii][n] = __builtin_amdgcn_mfma_f32_16x16x32_bf16(
                            af[ii][kk], bfr[n][kk], acc[p * 2 + ii][n], 0, 0, 0);
            __builtin_amdgcn_s_setprio(0);
        }
        // tile boundary: staged loads (issued phases 0-3) drained + published
        asm volatile("s_waitcnt vmcnt(0)" ::: "memory");
        __builtin_amdgcn_s_barrier();
        __builtin_amdgcn_sched_barrier(0);
    }

    // epilogue: C/D layout col=lane&15, row=(lane>>4)*4+reg (verified m89)
#pragma unroll
    for (int n = 0; n < 4; ++n) {
        const int col = bn + wn * 64 + n * 16 + r15;
        const float bv = bias[col];
#pragma unroll
        for (int i = 0; i < 8; ++i) {
#pragma unroll
            for (int jj = 0; jj < 4; ++jj) {
                const int row = bm + wm * 128 + i * 16 + g4 * 4 + jj;
                float v = acc[i][n][jj] + bv;
                if (RELU) v = fmaxf(v, 0.f);
                outb[(size_t)row * N + col] = (bf16_t)v;
            }
        }
    }
}

// ---------------- main bf16 MFMA GEMM (128x128): embed / proj / ff2 ----------------
template<bool RELU, bool HAS_RES>
__global__ __launch_bounds__(256, 3) void gemm_k(
    const bf16_t* __restrict__ A, const bf16_t* __restrict__ W,
    const float* __restrict__ bias, const bf16_t* __restrict__ res,
    bf16_t* __restrict__ outb, int M, int N, int K)
{
    __shared__ __align__(16) bf16_t As[128 * 64];
    __shared__ __align__(16) bf16_t Bs[128 * 64];
    const int tid  = threadIdx.x;
    const int lane = tid & 63;
    const int w    = tid >> 6;
    const int wr   = w >> 1, wc = w & 1;
    const int nwg  = gridDim.x * gridDim.y;
    const int flat = xcd_swz(blockIdx.y * gridDim.x + blockIdx.x, nwg);
    const int bm   = (flat / gridDim.x) * 128;
    const int bn   = (flat % gridDim.x) * 128;
    const int r15  = lane & 15;
    const int g4   = lane >> 4;

    int rs[4], cs[4];
#pragma unroll
    for (int j = 0; j < 4; ++j) {
        int slot = w * 4 + j;
        int r = slot * 8 + (lane >> 3);
        rs[j] = r;
        cs[j] = (lane & 7) ^ (r & 7);
    }

    f32x4 acc[4][4];
#pragma unroll
    for (int m = 0; m < 4; ++m)
#pragma unroll
        for (int n = 0; n < 4; ++n) acc[m][n] = (f32x4){0.f, 0.f, 0.f, 0.f};

    for (int kt = 0; kt < K; kt += 64) {
#pragma unroll
        for (int j = 0; j < 4; ++j) {
            int slot = w * 4 + j;
            gld_lds16(A + (size_t)(bm + rs[j]) * K + kt + cs[j] * 8, As + slot * 512);
            gld_lds16(W + (size_t)(bn + rs[j]) * K + kt + cs[j] * 8, Bs + slot * 512);
        }
        __syncthreads();
#pragma unroll
        for (int kk = 0; kk < 2; ++kk) {
            bf16x8 af[4], bfr[4];
#pragma unroll
            for (int m = 0; m < 4; ++m) {
                int r = wr * 64 + m * 16 + r15;
                int c = (kk * 4 + g4) ^ (r & 7);
                af[m] = *(const bf16x8*)(As + r * 64 + c * 8);
            }
#pragma unroll
            for (int n = 0; n < 4; ++n) {
                int r = wc * 64 + n * 16 + r15;
                int c = (kk * 4 + g4) ^ (r & 7);
                bfr[n] = *(const bf16x8*)(Bs + r * 64 + c * 8);
            }
#pragma unroll
            for (int m = 0; m < 4; ++m)
#pragma unroll
                for (int n = 0; n < 4; ++n)
                    acc[m][n] = __builtin_amdgcn_mfma_f32_16x16x32_bf16(af[m], bfr[n], acc[m][n], 0, 0, 0);
        }
        __syncthreads();
    }

    const int row0 = bm + wr * 64 + g4 * 4;
    const int col0 = bn + wc * 64 + r15;
#pragma unroll
    for (int n = 0; n < 4; ++n) {
        const int col = col0 + n * 16;
        const float bv = bias[col];
#pragma unroll
        for (int m = 0; m < 4; ++m) {
#pragma unroll
            for (int j = 0; j < 4; ++j) {
                const int row = row0 + m * 16 + j;
                size_t off = (size_t)row * N + col;
                float v = acc[m][n][j] + bv;
                if (HAS_RES) v += (float)res[off];
                if (RELU) v = fmaxf(v, 0.f);
                outb[off] = (bf16_t)v;
            }
        }
    }
}

// ---------------- flash attention (bf16 MFMA), no-max softmax, 8 waves / 128 q-rows ----------
__global__ __launch_bounds__(512, 2) void attn_k(const bf16_t* __restrict__ qkv, bf16_t* __restrict__ out) {
    const int bid  = xcd_swz(blockIdx.x, gridDim.x);
    const int qblk = bid & 3;
    const int h    = (bid >> 2) & 7;
    const int bb   = bid >> 5;
    const int tid  = threadIdx.x;
    const int lane = tid & 63;
    const int w    = tid >> 6;
    const int r15  = lane & 15;
    const int g4   = lane >> 4;

    __shared__ __align__(16) bf16_t Ks[64 * 64];
    __shared__ __align__(16) bf16_t VT[64 * 72];
    __shared__ __align__(16) bf16_t Ps[8][16 * 72];

    const size_t base = (size_t)bb * Sd * 1536;
    const int q0 = qblk * 128 + w * 16;

    bf16x8 qf[2];
    {
        const int qr = q0 + r15;
#pragma unroll
        for (int kk = 0; kk < 2; ++kk)
            qf[kk] = *(const bf16x8*)(qkv + base + (size_t)qr * 1536 + h * 64 + kk * 32 + g4 * 8);
    }

    f32x4 oacc[4];
#pragma unroll
    for (int dg = 0; dg < 4; ++dg) oacc[dg] = (f32x4){0.f, 0.f, 0.f, 0.f};
    float lrun[4] = {0.f, 0.f, 0.f, 0.f};

    for (int kv0 = 0; kv0 < Sd; kv0 += 64) {
        __syncthreads();
        {
            const int r = tid >> 3, c = tid & 7;
            const int cl = c ^ (r & 7);
            gld_lds16(qkv + base + (size_t)(kv0 + r) * 1536 + 512 + h * 64 + cl * 8,
                      Ks + (w * 64) * 8);
        }
        if (tid < 256) {
            const int r2 = tid >> 3, c = tid & 7;
            const bf16_t* vc = qkv + base + (size_t)(kv0 + 2 * r2) * 1536 + 1024 + h * 64 + c * 8;
            uint4 va = *(const uint4*)vc;
            uint4 vb = *(const uint4*)(vc + 1536);
            const u16* pa = (const u16*)&va;
            const u16* pb = (const u16*)&vb;
            const int rx = (2 * r2) ^ (c << 3);
#pragma unroll
            for (int e = 0; e < 8; ++e) {
                u32 wv = (u32)pa[e] | ((u32)pb[e] << 16);
                *(u32*)(VT + (c * 8 + e) * 72 + rx) = wv;
            }
        }
        __syncthreads();

        f32x4 sreg[4];
#pragma unroll
        for (int cg = 0; cg < 4; ++cg) {
            f32x4 a = (f32x4){0.f, 0.f, 0.f, 0.f};
#pragma unroll
            for (int kk = 0; kk < 2; ++kk) {
                int rk = cg * 16 + r15;
                int ck = (kk * 4 + g4) ^ (rk & 7);
                bf16x8 kf = *(const bf16x8*)(Ks + rk * 64 + ck * 8);
                a = __builtin_amdgcn_mfma_f32_16x16x32_bf16(qf[kk], kf, a, 0, 0, 0);
            }
            sreg[cg] = a * 0.125f;
        }

        float rsum[4] = {0.f, 0.f, 0.f, 0.f};
#pragma unroll
        for (int cg = 0; cg < 4; ++cg)
#pragma unroll
            for (int j = 0; j < 4; ++j) {
                float pv = __expf(sreg[cg][j]);
                sreg[cg][j] = pv;
                rsum[j] += pv;
            }
#pragma unroll
        for (int j = 0; j < 4; ++j) {
#pragma unroll
            for (int o = 1; o < 16; o <<= 1) rsum[j] += __shfl_xor(rsum[j], o);
            lrun[j] += rsum[j];
        }

#pragma unroll
        for (int cg = 0; cg < 4; ++cg)
#pragma unroll
            for (int j = 0; j < 4; ++j)
                Ps[w][(g4 * 4 + j) * 72 + cg * 16 + r15] = (bf16_t)sreg[cg][j];

        bf16x8 pf[2];
#pragma unroll
        for (int kk = 0; kk < 2; ++kk)
            pf[kk] = *(const bf16x8*)(&Ps[w][0] + r15 * 72 + kk * 32 + g4 * 8);

#pragma unroll
        for (int dg = 0; dg < 4; ++dg)
#pragma unroll
            for (int kk = 0; kk < 2; ++kk) {
                const int d = dg * 16 + r15;
                const int kvx = (kk * 32 + g4 * 8) ^ (((d >> 3) & 7) << 3);
                bf16x8 vf = *(const bf16x8*)(VT + d * 72 + kvx);
                oacc[dg] = __builtin_amdgcn_mfma_f32_16x16x32_bf16(pf[kk], vf, oacc[dg], 0, 0, 0);
            }
    }

#pragma unroll
    for (int dg = 0; dg < 4; ++dg)
#pragma unroll
        for (int j = 0; j < 4; ++j) {
            int row = q0 + g4 * 4 + j;
            out[(size_t)(bb * Sd + row) * Dd + h * 64 + dg * 16 + r15] = (bf16_t)(oacc[dg][j] / lrun[j]);
        }
}

// ---------------- LayerNorm over D=512 (bf16 in -> bf16 out); wave per row ----------------
__global__ __launch_bounds__(256) void ln_k(const bf16_t* __restrict__ in, const float* __restrict__ gg,
                                            const float* __restrict__ bb, bf16_t* __restrict__ outb) {
    const int w = threadIdx.x >> 6, lane = threadIdx.x & 63;
    const size_t row = (size_t)blockIdx.x * 4 + w;
    const int col = lane * 8;
    bf16x8 xv = *(const bf16x8*)(in + row * 512 + col);
    float x[8];
#pragma unroll
    for (int i = 0; i < 8; ++i) x[i] = (float)xv[i];
    float s = 0.f, sq = 0.f;
#pragma unroll
    for (int i = 0; i < 8; ++i) { s += x[i]; sq += x[i] * x[i]; }
#pragma unroll
    for (int o = 1; o < 64; o <<= 1) { s += __shfl_xor(s, o); sq += __shfl_xor(sq, o); }
    const float mean = s * (1.f / 512.f);
    const float var  = sq * (1.f / 512.f) - mean * mean;
    const float rstd = rsqrtf(var + 1e-5f);
    const float4 g0 = *(const float4*)(gg + col), g1 = *(const float4*)(gg + col + 4);
    const float4 b0 = *(const float4*)(bb + col), b1 = *(const float4*)(bb + col + 4);
    const float g[8] = {g0.x, g0.y, g0.z, g0.w, g1.x, g1.y, g1.z, g1.w};
    const float b[8] = {b0.x, b0.y, b0.z, b0.w, b1.x, b1.y, b1.z, b1.w};
    bf16x8 ob;
#pragma unroll
    for (int i = 0; i < 8; ++i) ob[i] = (bf16_t)((x[i] - mean) * rstd * g[i] + b[i]);
    *(bf16x8*)(outb + row * 512 + col) = ob;
}

// ---------------- head: 4 projections of h=x[:,-1] (bf16 spine) -> d_out (fp32), z sampling ----
__global__ __launch_bounds__(256) void head_k(const bf16_t* __restrict__ xsp,
                                              const float* __restrict__ Wm, const float* __restrict__ bm,
                                              const float* __restrict__ Wlv, const float* __restrict__ blv,
                                              const float* __restrict__ Wsc, const float* __restrict__ bsc,
                                              const float* __restrict__ Wsh, const float* __restrict__ bsh,
                                              const float* __restrict__ pi, const float* __restrict__ eps,
                                              const float* __restrict__ u, const float* __restrict__ choice,
                                              float* __restrict__ outp, float* __restrict__ z) {
    const int b = blockIdx.x;
    const int tid = threadIdx.x;
    __shared__ __align__(16) float hl[512];
    __shared__ float dots[4][64];
    const bf16_t* h = xsp + (size_t)(b * Sd + (Sd - 1)) * Dd;
    for (int i = tid; i < 512; i += 256) hl[i] = (float)h[i];
    __syncthreads();
    const int head = tid >> 6, zi = tid & 63;
    const float* Wp = head == 0 ? Wm : head == 1 ? Wlv : head == 2 ? Wsc : Wsh;
    const float* bp = head == 0 ? bm : head == 1 ? blv : head == 2 ? bsc : bsh;
    const float4* w4 = (const float4*)(Wp + zi * 512);
    const float4* h4 = (const float4*)hl;
    float acc = 0.f;
    for (int k = 0; k < 128; ++k) {
        float4 x = h4[k], y = w4[k];
        acc += x.x * y.x + x.y * y.y + x.z * y.z + x.w * y.w;
    }
    acc += bp[zi];
    float outv = (head == 2) ? __expf(acc) : acc;
    dots[head][zi] = outv;
    outp[FUTd * Bd + head * (Bd * Zd) + b * Zd + zi] = outv;
    __syncthreads();
    if (tid < 64) {
        float mean = dots[0][tid], lv = dots[1][tid], sc = dots[2][tid], sh = dots[3][tid];
        float a0 = pi[0], a1 = pi[1];
        float mx = fmaxf(a0, a1);
        float e0 = __expf(a0 - mx), e1 = __expf(a1 - mx);
        float pi0 = e0 / (e0 + e1);
        float zg = mean + eps[b * 64 + tid] * __expf(0.5f * lv);
        float uu = u[b * 64 + tid];
        float zp = sc / sh * (powf(1.f - uu, -sh) - 1.f);
        z[b * 64 + tid] = (choice[b] < pi0) ? zg : zp;
    }
}

// ---------------- small fp32 GEMM for the MLP tail (fp32 out) ----------------
template<bool RELU>
__global__ void sgemm_k(const float* __restrict__ A, const float* __restrict__ W,
                        const float* __restrict__ bias, float* __restrict__ outf,
                        int M, int N, int K) {
    int idx = blockIdx.x * 256 + threadIdx.x;
    if (idx >= M * N) return;
    int row = idx / N, col = idx - row * N;
    const float4* a4 = (const float4*)(A + (size_t)row * K);
    const float4* w4 = (const float4*)(W + (size_t)col * K);
    float acc = 0.f;
    for (int k = 0; k < (K >> 2); ++k) {
        float4 x = a4[k], y = w4[k];
        acc += x.x * y.x + x.y * y.y + x.z * y.z + x.w * y.w;
    }
    acc += bias[col];
    if (RELU) acc = fmaxf(acc, 0.f);
    outf[idx] = acc;
}

extern "C" void kernel_launch(void* const* d_in, const int* in_sizes, int n_in,
                              void* d_out, int out_size, void* d_ws, size_t ws_size,
                              hipStream_t stream) {
    const float* X      = (const float*)d_in[0];
    const float* eps    = (const float*)d_in[1];
    const float* u      = (const float*)d_in[2];
    const float* choice = (const float*)d_in[3];
    const float* We     = (const float*)d_in[4];
    const float* be     = (const float*)d_in[5];
    const float* Wqkv   = (const float*)d_in[6];
    const float* bqkv   = (const float*)d_in[7];
    const float* Wo     = (const float*)d_in[8];
    const float* bo     = (const float*)d_in[9];
    const float* ln1g   = (const float*)d_in[10];
    const float* ln1b   = (const float*)d_in[11];
    const float* W1     = (const float*)d_in[12];
    const float* b1     = (const float*)d_in[13];
    const float* W2     = (const float*)d_in[14];
    const float* b2     = (const float*)d_in[15];
    const float* ln2g   = (const float*)d_in[16];
    const float* ln2b   = (const float*)d_in[17];
    const float* Wm     = (const float*)d_in[18];
    const float* bm     = (const float*)d_in[19];
    const float* Wlv    = (const float*)d_in[20];
    const float* blv    = (const float*)d_in[21];
    const float* Wsc    = (const float*)d_in[22];
    const float* bsc    = (const float*)d_in[23];
    const float* Wsh    = (const float*)d_in[24];
    const float* bsh    = (const float*)d_in[25];
    const float* pip    = (const float*)d_in[26];
    const float* Wfc1   = (const float*)d_in[27];
    const float* bfc1   = (const float*)d_in[28];
    const float* Wfc2   = (const float*)d_in[29];
    const float* bfc2   = (const float*)d_in[30];
    const float* Wout   = (const float*)d_in[31];
    const float* bout   = (const float*)d_in[32];
    const float* Wfin   = (const float*)d_in[33];
    const float* bfin   = (const float*)d_in[34];
    float* outp = (float*)d_out;

    const int BS  = Bd * Sd;        // 32768 rows
    const int BSH = BS / 2;         // 16384 rows

    char* p = (char*)d_ws;
    auto alloc = [&](size_t bytes) { char* r = p; p += (bytes + 255) & ~(size_t)255; return r; };
    bf16_t* We_b   = (bf16_t*)alloc((size_t)Dd * 64 * 2);
    bf16_t* Wqkv_b = (bf16_t*)alloc((size_t)Ld * 3 * Dd * Dd * 2);
    bf16_t* Wo_b   = (bf16_t*)alloc((size_t)Ld * Dd * Dd * 2);
    bf16_t* W1_b   = (bf16_t*)alloc((size_t)Ld * FFd * Dd * 2);
    bf16_t* W2_b   = (bf16_t*)alloc((size_t)Ld * Dd * FFd * 2);
    bf16_t* Xb     = (bf16_t*)alloc((size_t)BS * 64 * 2);
    bf16_t* xa     = (bf16_t*)alloc((size_t)BS * Dd * 2);
    bf16_t* xpre   = (bf16_t*)alloc((size_t)BS * Dd * 2);
    bf16_t* sbuf   = (bf16_t*)alloc((size_t)BSH * FFd * 2);
    float*  zbuf   = (float*)alloc((size_t)Bd * Zd * 4);
    float*  d1     = (float*)alloc((size_t)Bd * 128 * 4);
    float*  d2     = (float*)alloc((size_t)Bd * 500 * 4);
    float*  o3     = (float*)alloc((size_t)Bd * FUTd * 4);
    size_t needed = (size_t)(p - (char*)d_ws);
    if (ws_size < needed) return;

    auto cg = [](int n4) { return (n4 + 255) / 256; };
    cvt_k<<<cg(Dd * 64 / 4), 256, 0, stream>>>(We, We_b, Dd * 64 / 4);
    cvt_k<<<cg(Ld * 3 * Dd * Dd / 4), 256, 0, stream>>>(Wqkv, Wqkv_b, Ld * 3 * Dd * Dd / 4);
    cvt_k<<<cg(Ld * Dd * Dd / 4), 256, 0, stream>>>(Wo, Wo_b, Ld * Dd * Dd / 4);
    cvt_k<<<cg(Ld * FFd * Dd / 4), 256, 0, stream>>>(W1, W1_b, Ld * FFd * Dd / 4);
    cvt_k<<<cg(Ld * Dd * FFd / 4), 256, 0, stream>>>(W2, W2_b, Ld * Dd * FFd / 4);
    cvt_k<<<cg(BS * 64 / 4), 256, 0, stream>>>(X, Xb, BS * 64 / 4);

    // embed: xa = X @ We^T + be (bf16)
    gemm_k<false, false><<<dim3(Dd / 128, BS / 128), 256, 0, stream>>>(
        Xb, We_b, be, nullptr, xa, BS, Dd, 64);

    bf16_t* attno = sbuf + (size_t)BSH * 1536;

    for (int l = 0; l < Ld; ++l) {
        for (int hb = 0; hb < 2; ++hb) {
            bf16_t* xa_h   = xa   + (size_t)hb * BSH * Dd;
            bf16_t* xpre_h = xpre + (size_t)hb * BSH * Dd;
            // qkv: 256^2 8-phase-lite (384 blocks, 512 thr)
            gemm256_k<false><<<dim3(3 * Dd / 256, BSH / 256), 512, 0, stream>>>(
                xa_h, Wqkv_b + (size_t)l * 3 * Dd * Dd, bqkv + (size_t)l * 3 * Dd,
                sbuf, BSH, 3 * Dd, Dd);
            attn_k<<<(Bd / 2) * Hd * (Sd / 128), 512, 0, stream>>>(sbuf, attno);
            gemm_k<false, true><<<dim3(Dd / 128, BSH / 128), 256, 0, stream>>>(
                attno, Wo_b + (size_t)l * Dd * Dd, bo + (size_t)l * Dd, xa_h,
                xpre_h, BSH, Dd, Dd);
        }
        ln_k<<<BS / 4, 256, 0, stream>>>(xpre, ln1g + (size_t)l * Dd, ln1b + (size_t)l * Dd, xa);
        for (int hb = 0; hb < 2; ++hb) {
            bf16_t* xa_h   = xa   + (size_t)hb * BSH * Dd;
            bf16_t* xpre_h = xpre + (size_t)hb * BSH * Dd;
            // ff1: 256^2 8-phase-lite (512 blocks, 512 thr), fused relu
            gemm256_k<true><<<dim3(FFd / 256, BSH / 256), 512, 0, stream>>>(
                xa_h, W1_b + (size_t)l * FFd * Dd, b1 + (size_t)l * FFd,
                sbuf, BSH, FFd, Dd);
            gemm_k<false, true><<<dim3(Dd / 128, BSH / 128), 256, 0, stream>>>(
                sbuf, W2_b + (size_t)l * Dd * FFd, b2 + (size_t)l * Dd, xa_h,
                xpre_h, BSH, Dd, FFd);
        }
        ln_k<<<BS / 4, 256, 0, stream>>>(xpre, ln2g + (size_t)l * Dd, ln2b + (size_t)l * Dd, xa);
    }

    head_k<<<Bd, 256, 0, stream>>>(xa, Wm, bm, Wlv, blv, Wsc, bsc, Wsh, bsh,
                                   pip, eps, u, choice, outp, zbuf);
    sgemm_k<true ><<<(Bd * 128 + 255) / 256, 256, 0, stream>>>(zbuf, Wfc1, bfc1, d1, Bd, 128, Zd);
    sgemm_k<true ><<<(Bd * 500 + 255) / 256, 256, 0, stream>>>(d1, Wfc2, bfc2, d2, Bd, 500, 128);
    sgemm_k<false><<<(Bd * FUTd + 255) / 256, 256, 0, stream>>>(d2, Wout, bout, o3, Bd, FUTd, 500);
    sgemm_k<false><<<(Bd * FUTd + 255) / 256, 256, 0, stream>>>(o3, Wfin, bfin, outp, Bd, FUTd, FUTd);
}

// Round 18
// 1668.881 us; speedup vs baseline: 1.2001x; 1.2001x over previous
//
#include <hip/hip_runtime.h>
#include <hip/hip_bf16.h>
#include <stdint.h>

typedef __bf16 bf16_t;
typedef __bf16 bf16x8 __attribute__((ext_vector_type(8)));
typedef __bf16 bf16x4 __attribute__((ext_vector_type(4)));
typedef float f32x4 __attribute__((ext_vector_type(4)));
typedef unsigned int u32;
typedef unsigned short u16;

static constexpr int Bd = 64, Sd = 512, Dd = 512, Hd = 8, Ld = 4, FFd = 2048, Zd = 64, FUTd = 96;

// ---------------- bijective XCD-aware block swizzle (T1, m204 form) ----------------
__device__ __forceinline__ int xcd_swz(int flat, int nwg) {
    int q = nwg >> 3, r = nwg & 7;
    int xcd = flat & 7, idx = flat >> 3;
    return (xcd < r ? xcd * (q + 1) : r * (q + 1) + (xcd - r) * q) + idx;
}

// ---------------- async global->LDS (16B per lane, wave-uniform LDS base) ----------------
__device__ __forceinline__ void gld_lds16(const bf16_t* g, bf16_t* l) {
    __builtin_amdgcn_global_load_lds(
        (const __attribute__((address_space(1))) u32*)g,
        (__attribute__((address_space(3))) u32*)l, 16, 0, 0);
}

// ---------------- fp32 -> bf16 conversion (vectorized x4) ----------------
__global__ void cvt_k(const float* __restrict__ in, bf16_t* __restrict__ out, int n4) {
    int i = blockIdx.x * 256 + threadIdx.x;
    if (i >= n4) return;
    float4 v = ((const float4*)in)[i];
    bf16x4 o;
    o[0] = (bf16_t)v.x; o[1] = (bf16_t)v.y; o[2] = (bf16_t)v.z; o[3] = (bf16_t)v.w;
    ((bf16x4*)out)[i] = o;
}

// ---------------- main bf16 MFMA GEMM (128x128): C = A@W^T + bias [+res(bf16)] [relu] ----------
// Round-11/16 version (best measured): m97-style K-loop, direct scalar epilogue,
// both-sides chunk swizzle, gld_lds width-16, 3 blocks/CU.
template<bool RELU, bool HAS_RES>
__global__ __launch_bounds__(256, 3) void gemm_k(
    const bf16_t* __restrict__ A, const bf16_t* __restrict__ W,
    const float* __restrict__ bias, const bf16_t* __restrict__ res,
    bf16_t* __restrict__ outb, int M, int N, int K)
{
    __shared__ __align__(16) bf16_t As[128 * 64];
    __shared__ __align__(16) bf16_t Bs[128 * 64];
    const int tid  = threadIdx.x;
    const int lane = tid & 63;
    const int w    = tid >> 6;
    const int wr   = w >> 1, wc = w & 1;
    const int nwg  = gridDim.x * gridDim.y;
    const int flat = xcd_swz(blockIdx.y * gridDim.x + blockIdx.x, nwg);
    const int bm   = (flat / gridDim.x) * 128;
    const int bn   = (flat % gridDim.x) * 128;
    const int r15  = lane & 15;
    const int g4   = lane >> 4;

    int rs[4], cs[4];
#pragma unroll
    for (int j = 0; j < 4; ++j) {
        int slot = w * 4 + j;
        int r = slot * 8 + (lane >> 3);
        rs[j] = r;
        cs[j] = (lane & 7) ^ (r & 7);
    }

    f32x4 acc[4][4];
#pragma unroll
    for (int m = 0; m < 4; ++m)
#pragma unroll
        for (int n = 0; n < 4; ++n) acc[m][n] = (f32x4){0.f, 0.f, 0.f, 0.f};

    for (int kt = 0; kt < K; kt += 64) {
#pragma unroll
        for (int j = 0; j < 4; ++j) {
            int slot = w * 4 + j;
            gld_lds16(A + (size_t)(bm + rs[j]) * K + kt + cs[j] * 8, As + slot * 512);
            gld_lds16(W + (size_t)(bn + rs[j]) * K + kt + cs[j] * 8, Bs + slot * 512);
        }
        __syncthreads();
#pragma unroll
        for (int kk = 0; kk < 2; ++kk) {
            bf16x8 af[4], bfr[4];
#pragma unroll
            for (int m = 0; m < 4; ++m) {
                int r = wr * 64 + m * 16 + r15;
                int c = (kk * 4 + g4) ^ (r & 7);
                af[m] = *(const bf16x8*)(As + r * 64 + c * 8);
            }
#pragma unroll
            for (int n = 0; n < 4; ++n) {
                int r = wc * 64 + n * 16 + r15;
                int c = (kk * 4 + g4) ^ (r & 7);
                bfr[n] = *(const bf16x8*)(Bs + r * 64 + c * 8);
            }
#pragma unroll
            for (int m = 0; m < 4; ++m)
#pragma unroll
                for (int n = 0; n < 4; ++n)
                    acc[m][n] = __builtin_amdgcn_mfma_f32_16x16x32_bf16(af[m], bfr[n], acc[m][n], 0, 0, 0);
        }
        __syncthreads();
    }

    const int row0 = bm + wr * 64 + g4 * 4;
    const int col0 = bn + wc * 64 + r15;
#pragma unroll
    for (int n = 0; n < 4; ++n) {
        const int col = col0 + n * 16;
        const float bv = bias[col];
#pragma unroll
        for (int m = 0; m < 4; ++m) {
#pragma unroll
            for (int j = 0; j < 4; ++j) {
                const int row = row0 + m * 16 + j;
                size_t off = (size_t)row * N + col;
                float v = acc[m][n][j] + bv;
                if (HAS_RES) v += (float)res[off];
                if (RELU) v = fmaxf(v, 0.f);
                outb[off] = (bf16_t)v;
            }
        }
    }
}

// ---------------- flash attention (bf16 MFMA), no-max softmax, 8 waves / 128 q-rows ----------
// Round-16 version. Works for any batch count nb: grid = nb * Hd * (Sd/128).
__global__ __launch_bounds__(512, 2) void attn_k(const bf16_t* __restrict__ qkv, bf16_t* __restrict__ out) {
    const int bid  = xcd_swz(blockIdx.x, gridDim.x);
    const int qblk = bid & 3;
    const int h    = (bid >> 2) & 7;
    const int bb   = bid >> 5;
    const int tid  = threadIdx.x;
    const int lane = tid & 63;
    const int w    = tid >> 6;
    const int r15  = lane & 15;
    const int g4   = lane >> 4;

    __shared__ __align__(16) bf16_t Ks[64 * 64];
    __shared__ __align__(16) bf16_t VT[64 * 72];
    __shared__ __align__(16) bf16_t Ps[8][16 * 72];

    const size_t base = (size_t)bb * Sd * 1536;
    const int q0 = qblk * 128 + w * 16;

    bf16x8 qf[2];
    {
        const int qr = q0 + r15;
#pragma unroll
        for (int kk = 0; kk < 2; ++kk)
            qf[kk] = *(const bf16x8*)(qkv + base + (size_t)qr * 1536 + h * 64 + kk * 32 + g4 * 8);
    }

    f32x4 oacc[4];
#pragma unroll
    for (int dg = 0; dg < 4; ++dg) oacc[dg] = (f32x4){0.f, 0.f, 0.f, 0.f};
    float lrun[4] = {0.f, 0.f, 0.f, 0.f};

    for (int kv0 = 0; kv0 < Sd; kv0 += 64) {
        __syncthreads();
        {
            const int r = tid >> 3, c = tid & 7;
            const int cl = c ^ (r & 7);
            gld_lds16(qkv + base + (size_t)(kv0 + r) * 1536 + 512 + h * 64 + cl * 8,
                      Ks + (w * 64) * 8);
        }
        if (tid < 256) {
            const int r2 = tid >> 3, c = tid & 7;
            const bf16_t* vc = qkv + base + (size_t)(kv0 + 2 * r2) * 1536 + 1024 + h * 64 + c * 8;
            uint4 va = *(const uint4*)vc;
            uint4 vb = *(const uint4*)(vc + 1536);
            const u16* pa = (const u16*)&va;
            const u16* pb = (const u16*)&vb;
            const int rx = (2 * r2) ^ (c << 3);
#pragma unroll
            for (int e = 0; e < 8; ++e) {
                u32 wv = (u32)pa[e] | ((u32)pb[e] << 16);
                *(u32*)(VT + (c * 8 + e) * 72 + rx) = wv;
            }
        }
        __syncthreads();

        f32x4 sreg[4];
#pragma unroll
        for (int cg = 0; cg < 4; ++cg) {
            f32x4 a = (f32x4){0.f, 0.f, 0.f, 0.f};
#pragma unroll
            for (int kk = 0; kk < 2; ++kk) {
                int rk = cg * 16 + r15;
                int ck = (kk * 4 + g4) ^ (rk & 7);
                bf16x8 kf = *(const bf16x8*)(Ks + rk * 64 + ck * 8);
                a = __builtin_amdgcn_mfma_f32_16x16x32_bf16(qf[kk], kf, a, 0, 0, 0);
            }
            sreg[cg] = a * 0.125f;
        }

        float rsum[4] = {0.f, 0.f, 0.f, 0.f};
#pragma unroll
        for (int cg = 0; cg < 4; ++cg)
#pragma unroll
            for (int j = 0; j < 4; ++j) {
                float pv = __expf(sreg[cg][j]);
                sreg[cg][j] = pv;
                rsum[j] += pv;
            }
#pragma unroll
        for (int j = 0; j < 4; ++j) {
#pragma unroll
            for (int o = 1; o < 16; o <<= 1) rsum[j] += __shfl_xor(rsum[j], o);
            lrun[j] += rsum[j];
        }

#pragma unroll
        for (int cg = 0; cg < 4; ++cg)
#pragma unroll
            for (int j = 0; j < 4; ++j)
                Ps[w][(g4 * 4 + j) * 72 + cg * 16 + r15] = (bf16_t)sreg[cg][j];

        bf16x8 pf[2];
#pragma unroll
        for (int kk = 0; kk < 2; ++kk)
            pf[kk] = *(const bf16x8*)(&Ps[w][0] + r15 * 72 + kk * 32 + g4 * 8);

#pragma unroll
        for (int dg = 0; dg < 4; ++dg)
#pragma unroll
            for (int kk = 0; kk < 2; ++kk) {
                const int d = dg * 16 + r15;
                const int kvx = (kk * 32 + g4 * 8) ^ (((d >> 3) & 7) << 3);
                bf16x8 vf = *(const bf16x8*)(VT + d * 72 + kvx);
                oacc[dg] = __builtin_amdgcn_mfma_f32_16x16x32_bf16(pf[kk], vf, oacc[dg], 0, 0, 0);
            }
    }

#pragma unroll
    for (int dg = 0; dg < 4; ++dg)
#pragma unroll
        for (int j = 0; j < 4; ++j) {
            int row = q0 + g4 * 4 + j;
            out[(size_t)(bb * Sd + row) * Dd + h * 64 + dg * 16 + r15] = (bf16_t)(oacc[dg][j] / lrun[j]);
        }
}

// ---------------- LayerNorm over D=512 (bf16 in -> bf16 out); wave per row ----------------
__global__ __launch_bounds__(256) void ln_k(const bf16_t* __restrict__ in, const float* __restrict__ gg,
                                            const float* __restrict__ bb, bf16_t* __restrict__ outb) {
    const int w = threadIdx.x >> 6, lane = threadIdx.x & 63;
    const size_t row = (size_t)blockIdx.x * 4 + w;
    const int col = lane * 8;
    bf16x8 xv = *(const bf16x8*)(in + row * 512 + col);
    float x[8];
#pragma unroll
    for (int i = 0; i < 8; ++i) x[i] = (float)xv[i];
    float s = 0.f, sq = 0.f;
#pragma unroll
    for (int i = 0; i < 8; ++i) { s += x[i]; sq += x[i] * x[i]; }
#pragma unroll
    for (int o = 1; o < 64; o <<= 1) { s += __shfl_xor(s, o); sq += __shfl_xor(sq, o); }
    const float mean = s * (1.f / 512.f);
    const float var  = sq * (1.f / 512.f) - mean * mean;
    const float rstd = rsqrtf(var + 1e-5f);
    const float4 g0 = *(const float4*)(gg + col), g1 = *(const float4*)(gg + col + 4);
    const float4 b0 = *(const float4*)(bb + col), b1 = *(const float4*)(bb + col + 4);
    const float g[8] = {g0.x, g0.y, g0.z, g0.w, g1.x, g1.y, g1.z, g1.w};
    const float b[8] = {b0.x, b0.y, b0.z, b0.w, b1.x, b1.y, b1.z, b1.w};
    bf16x8 ob;
#pragma unroll
    for (int i = 0; i < 8; ++i) ob[i] = (bf16_t)((x[i] - mean) * rstd * g[i] + b[i]);
    *(bf16x8*)(outb + row * 512 + col) = ob;
}

// ---------------- head: 4 projections of h=x[:,-1] (bf16 spine) -> d_out (fp32), z sampling ----
__global__ __launch_bounds__(256) void head_k(const bf16_t* __restrict__ xsp,
                                              const float* __restrict__ Wm, const float* __restrict__ bm,
                                              const float* __restrict__ Wlv, const float* __restrict__ blv,
                                              const float* __restrict__ Wsc, const float* __restrict__ bsc,
                                              const float* __restrict__ Wsh, const float* __restrict__ bsh,
                                              const float* __restrict__ pi, const float* __restrict__ eps,
                                              const float* __restrict__ u, const float* __restrict__ choice,
                                              float* __restrict__ outp, float* __restrict__ z) {
    const int b = blockIdx.x;
    const int tid = threadIdx.x;
    __shared__ __align__(16) float hl[512];
    __shared__ float dots[4][64];
    const bf16_t* h = xsp + (size_t)(b * Sd + (Sd - 1)) * Dd;
    for (int i = tid; i < 512; i += 256) hl[i] = (float)h[i];
    __syncthreads();
    const int head = tid >> 6, zi = tid & 63;
    const float* Wp = head == 0 ? Wm : head == 1 ? Wlv : head == 2 ? Wsc : Wsh;
    const float* bp = head == 0 ? bm : head == 1 ? blv : head == 2 ? bsc : bsh;
    const float4* w4 = (const float4*)(Wp + zi * 512);
    const float4* h4 = (const float4*)hl;
    float acc = 0.f;
    for (int k = 0; k < 128; ++k) {
        float4 x = h4[k], y = w4[k];
        acc += x.x * y.x + x.y * y.y + x.z * y.z + x.w * y.w;
    }
    acc += bp[zi];
    float outv = (head == 2) ? __expf(acc) : acc;
    dots[head][zi] = outv;
    outp[FUTd * Bd + head * (Bd * Zd) + b * Zd + zi] = outv;
    __syncthreads();
    if (tid < 64) {
        float mean = dots[0][tid], lv = dots[1][tid], sc = dots[2][tid], sh = dots[3][tid];
        float a0 = pi[0], a1 = pi[1];
        float mx = fmaxf(a0, a1);
        float e0 = __expf(a0 - mx), e1 = __expf(a1 - mx);
        float pi0 = e0 / (e0 + e1);
        float zg = mean + eps[b * 64 + tid] * __expf(0.5f * lv);
        float uu = u[b * 64 + tid];
        float zp = sc / sh * (powf(1.f - uu, -sh) - 1.f);
        z[b * 64 + tid] = (choice[b] < pi0) ? zg : zp;
    }
}

// ---------------- small fp32 GEMM for the MLP tail (fp32 out) ----------------
template<bool RELU>
__global__ void sgemm_k(const float* __restrict__ A, const float* __restrict__ W,
                        const float* __restrict__ bias, float* __restrict__ outf,
                        int M, int N, int K) {
    int idx = blockIdx.x * 256 + threadIdx.x;
    if (idx >= M * N) return;
    int row = idx / N, col = idx - row * N;
    const float4* a4 = (const float4*)(A + (size_t)row * K);
    const float4* w4 = (const float4*)(W + (size_t)col * K);
    float acc = 0.f;
    for (int k = 0; k < (K >> 2); ++k) {
        float4 x = a4[k], y = w4[k];
        acc += x.x * y.x + x.y * y.y + x.z * y.z + x.w * y.w;
    }
    acc += bias[col];
    if (RELU) acc = fmaxf(acc, 0.f);
    outf[idx] = acc;
}

extern "C" void kernel_launch(void* const* d_in, const int* in_sizes, int n_in,
                              void* d_out, int out_size, void* d_ws, size_t ws_size,
                              hipStream_t stream) {
    const float* X      = (const float*)d_in[0];
    const float* eps    = (const float*)d_in[1];
    const float* u      = (const float*)d_in[2];
    const float* choice = (const float*)d_in[3];
    const float* We     = (const float*)d_in[4];
    const float* be     = (const float*)d_in[5];
    const float* Wqkv   = (const float*)d_in[6];
    const float* bqkv   = (const float*)d_in[7];
    const float* Wo     = (const float*)d_in[8];
    const float* bo     = (const float*)d_in[9];
    const float* ln1g   = (const float*)d_in[10];
    const float* ln1b   = (const float*)d_in[11];
    const float* W1     = (const float*)d_in[12];
    const float* b1     = (const float*)d_in[13];
    const float* W2     = (const float*)d_in[14];
    const float* b2     = (const float*)d_in[15];
    const float* ln2g   = (const float*)d_in[16];
    const float* ln2b   = (const float*)d_in[17];
    const float* Wm     = (const float*)d_in[18];
    const float* bm     = (const float*)d_in[19];
    const float* Wlv    = (const float*)d_in[20];
    const float* blv    = (const float*)d_in[21];
    const float* Wsc    = (const float*)d_in[22];
    const float* bsc    = (const float*)d_in[23];
    const float* Wsh    = (const float*)d_in[24];
    const float* bsh    = (const float*)d_in[25];
    const float* pip    = (const float*)d_in[26];
    const float* Wfc1   = (const float*)d_in[27];
    const float* bfc1   = (const float*)d_in[28];
    const float* Wfc2   = (const float*)d_in[29];
    const float* bfc2   = (const float*)d_in[30];
    const float* Wout   = (const float*)d_in[31];
    const float* bout   = (const float*)d_in[32];
    const float* Wfin   = (const float*)d_in[33];
    const float* bfin   = (const float*)d_in[34];
    float* outp = (float*)d_out;

    const int BS = Bd * Sd;          // 32768 rows

    // fixed allocations (independent of chunking)
    const size_t fixed_bytes =
        ((size_t)Dd * 64 * 2 + 255 & ~(size_t)255) +
        ((size_t)Ld * 3 * Dd * Dd * 2 + 255 & ~(size_t)255) +
        ((size_t)Ld * Dd * Dd * 2 + 255 & ~(size_t)255) +
        ((size_t)Ld * FFd * Dd * 2 + 255 & ~(size_t)255) +
        ((size_t)Ld * Dd * FFd * 2 + 255 & ~(size_t)255) +
        ((size_t)BS * 64 * 2 + 255 & ~(size_t)255) +
        ((size_t)BS * Dd * 2 + 255 & ~(size_t)255) * 2 +
        ((size_t)Bd * Zd * 4 + 255 & ~(size_t)255) +
        ((size_t)Bd * 128 * 4 + 255 & ~(size_t)255) +
        ((size_t)Bd * 500 * 4 + 255 & ~(size_t)255) +
        ((size_t)Bd * FUTd * 4 + 255 & ~(size_t)255) + 4096;
    // pick largest chunk (full batch preferred) that fits the workspace
    int BSC = BS;                    // chunk rows for the sublayer scratch
    while (BSC >= 4096 && fixed_bytes + (size_t)BSC * FFd * 2 > ws_size) BSC >>= 1;
    const int nch = BS / BSC;        // number of chunks

    char* p = (char*)d_ws;
    auto alloc = [&](size_t bytes) { char* r = p; p += (bytes + 255) & ~(size_t)255; return r; };
    bf16_t* We_b   = (bf16_t*)alloc((size_t)Dd * 64 * 2);
    bf16_t* Wqkv_b = (bf16_t*)alloc((size_t)Ld * 3 * Dd * Dd * 2);
    bf16_t* Wo_b   = (bf16_t*)alloc((size_t)Ld * Dd * Dd * 2);
    bf16_t* W1_b   = (bf16_t*)alloc((size_t)Ld * FFd * Dd * 2);
    bf16_t* W2_b   = (bf16_t*)alloc((size_t)Ld * Dd * FFd * 2);
    bf16_t* Xb     = (bf16_t*)alloc((size_t)BS * 64 * 2);
    bf16_t* xa     = (bf16_t*)alloc((size_t)BS * Dd * 2);    // current x (post-LN / embed out)
    bf16_t* xpre   = (bf16_t*)alloc((size_t)BS * Dd * 2);    // pre-LN accumulator
    bf16_t* sbuf   = (bf16_t*)alloc((size_t)BSC * FFd * 2);  // qkv+attno OR ff1, per chunk
    float*  zbuf   = (float*)alloc((size_t)Bd * Zd * 4);
    float*  d1     = (float*)alloc((size_t)Bd * 128 * 4);
    float*  d2     = (float*)alloc((size_t)Bd * 500 * 4);
    float*  o3     = (float*)alloc((size_t)Bd * FUTd * 4);
    size_t needed = (size_t)(p - (char*)d_ws);
    if (ws_size < needed) return;    // BSC floor hit and still too small: clean fail

    auto cg = [](int n4) { return (n4 + 255) / 256; };
    cvt_k<<<cg(Dd * 64 / 4), 256, 0, stream>>>(We, We_b, Dd * 64 / 4);
    cvt_k<<<cg(Ld * 3 * Dd * Dd / 4), 256, 0, stream>>>(Wqkv, Wqkv_b, Ld * 3 * Dd * Dd / 4);
    cvt_k<<<cg(Ld * Dd * Dd / 4), 256, 0, stream>>>(Wo, Wo_b, Ld * Dd * Dd / 4);
    cvt_k<<<cg(Ld * FFd * Dd / 4), 256, 0, stream>>>(W1, W1_b, Ld * FFd * Dd / 4);
    cvt_k<<<cg(Ld * Dd * FFd / 4), 256, 0, stream>>>(W2, W2_b, Ld * Dd * FFd / 4);
    cvt_k<<<cg(BS * 64 / 4), 256, 0, stream>>>(X, Xb, BS * 64 / 4);

    // embed: xa = X @ We^T + be (bf16)
    gemm_k<false, false><<<dim3(Dd / 128, BS / 128), 256, 0, stream>>>(
        Xb, We_b, be, nullptr, xa, BS, Dd, 64);

    bf16_t* attno = sbuf + (size_t)BSC * 1536;   // tail of sbuf (1536+512 = 2048 = FFd elems/row)

    for (int l = 0; l < Ld; ++l) {
        for (int hb = 0; hb < nch; ++hb) {
            bf16_t* xa_h   = xa   + (size_t)hb * BSC * Dd;
            bf16_t* xpre_h = xpre + (size_t)hb * BSC * Dd;
            gemm_k<false, false><<<dim3(3 * Dd / 128, BSC / 128), 256, 0, stream>>>(
                xa_h, Wqkv_b + (size_t)l * 3 * Dd * Dd, bqkv + (size_t)l * 3 * Dd, nullptr,
                sbuf, BSC, 3 * Dd, Dd);
            attn_k<<<(BSC / Sd) * Hd * (Sd / 128), 512, 0, stream>>>(sbuf, attno);
            // proj + residual(xa) -> xpre
            gemm_k<false, true><<<dim3(Dd / 128, BSC / 128), 256, 0, stream>>>(
                attno, Wo_b + (size_t)l * Dd * Dd, bo + (size_t)l * Dd, xa_h,
                xpre_h, BSC, Dd, Dd);
        }
        // ln1: xpre -> xa (full batch)
        ln_k<<<BS / 4, 256, 0, stream>>>(xpre, ln1g + (size_t)l * Dd, ln1b + (size_t)l * Dd, xa);
        for (int hb = 0; hb < nch; ++hb) {
            bf16_t* xa_h   = xa   + (size_t)hb * BSC * Dd;
            bf16_t* xpre_h = xpre + (size_t)hb * BSC * Dd;
            gemm_k<true, false><<<dim3(FFd / 128, BSC / 128), 256, 0, stream>>>(
                xa_h, W1_b + (size_t)l * FFd * Dd, b1 + (size_t)l * FFd, nullptr,
                sbuf, BSC, FFd, Dd);
            // ff2 + residual(xa) -> xpre
            gemm_k<false, true><<<dim3(Dd / 128, BSC / 128), 256, 0, stream>>>(
                sbuf, W2_b + (size_t)l * Dd * FFd, b2 + (size_t)l * Dd, xa_h,
                xpre_h, BSC, Dd, FFd);
        }
        // ln2: xpre -> xa
        ln_k<<<BS / 4, 256, 0, stream>>>(xpre, ln2g + (size_t)l * Dd, ln2b + (size_t)l * Dd, xa);
    }

    // head: mean/logvar/scale/shape -> d_out[6144..22527] (fp32), z -> zbuf
    head_k<<<Bd, 256, 0, stream>>>(xa, Wm, bm, Wlv, blv, Wsc, bsc, Wsh, bsh,
                                   pip, eps, u, choice, outp, zbuf);
    // MLP tail (fp32); rec -> d_out[0..6143] (fp32)
    sgemm_k<true ><<<(Bd * 128 + 255) / 256, 256, 0, stream>>>(zbuf, Wfc1, bfc1, d1, Bd, 128, Zd);
    sgemm_k<true ><<<(Bd * 500 + 255) / 256, 256, 0, stream>>>(d1, Wfc2, bfc2, d2, Bd, 500, 128);
    sgemm_k<false><<<(Bd * FUTd + 255) / 256, 256, 0, stream>>>(d2, Wout, bout, o3, Bd, FUTd, 500);
    sgemm_k<false><<<(Bd * FUTd + 255) / 256, 256, 0, stream>>>(o3, Wfin, bfin, outp, Bd, FUTd, FUTd);
}

// Round 19
// 1666.232 us; speedup vs baseline: 1.2020x; 1.0016x over previous
//
#include <hip/hip_runtime.h>
#include <hip/hip_bf16.h>
#include <stdint.h>

typedef __bf16 bf16_t;
typedef __bf16 bf16x8 __attribute__((ext_vector_type(8)));
typedef __bf16 bf16x4 __attribute__((ext_vector_type(4)));
typedef float f32x4 __attribute__((ext_vector_type(4)));
typedef unsigned int u32;
typedef unsigned short u16;

static constexpr int Bd = 64, Sd = 512, Dd = 512, Hd = 8, Ld = 4, FFd = 2048, Zd = 64, FUTd = 96;

// ---------------- bijective XCD-aware block swizzle (T1, m204 form) ----------------
__device__ __forceinline__ int xcd_swz(int flat, int nwg) {
    int q = nwg >> 3, r = nwg & 7;
    int xcd = flat & 7, idx = flat >> 3;
    return (xcd < r ? xcd * (q + 1) : r * (q + 1) + (xcd - r) * q) + idx;
}

// ---------------- async global->LDS (16B per lane, wave-uniform LDS base) ----------------
__device__ __forceinline__ void gld_lds16(const bf16_t* g, bf16_t* l) {
    __builtin_amdgcn_global_load_lds(
        (const __attribute__((address_space(1))) u32*)g,
        (__attribute__((address_space(3))) u32*)l, 16, 0, 0);
}

// ---------------- fp32 -> bf16 conversion (vectorized x4) ----------------
__global__ void cvt_k(const float* __restrict__ in, bf16_t* __restrict__ out, int n4) {
    int i = blockIdx.x * 256 + threadIdx.x;
    if (i >= n4) return;
    float4 v = ((const float4*)in)[i];
    bf16x4 o;
    o[0] = (bf16_t)v.x; o[1] = (bf16_t)v.y; o[2] = (bf16_t)v.z; o[3] = (bf16_t)v.w;
    ((bf16x4*)out)[i] = o;
}

// ---------------- main bf16 MFMA GEMM (128x128): C = A@W^T + bias [+res(bf16)] [relu] ----------
template<bool RELU, bool HAS_RES>
__global__ __launch_bounds__(256, 3) void gemm_k(
    const bf16_t* __restrict__ A, const bf16_t* __restrict__ W,
    const float* __restrict__ bias, const bf16_t* __restrict__ res,
    bf16_t* __restrict__ outb, int M, int N, int K)
{
    __shared__ __align__(16) bf16_t As[128 * 64];
    __shared__ __align__(16) bf16_t Bs[128 * 64];
    const int tid  = threadIdx.x;
    const int lane = tid & 63;
    const int w    = tid >> 6;
    const int wr   = w >> 1, wc = w & 1;
    const int nwg  = gridDim.x * gridDim.y;
    const int flat = xcd_swz(blockIdx.y * gridDim.x + blockIdx.x, nwg);
    const int bm   = (flat / gridDim.x) * 128;
    const int bn   = (flat % gridDim.x) * 128;
    const int r15  = lane & 15;
    const int g4   = lane >> 4;

    int rs[4], cs[4];
#pragma unroll
    for (int j = 0; j < 4; ++j) {
        int slot = w * 4 + j;
        int r = slot * 8 + (lane >> 3);
        rs[j] = r;
        cs[j] = (lane & 7) ^ (r & 7);
    }

    f32x4 acc[4][4];
#pragma unroll
    for (int m = 0; m < 4; ++m)
#pragma unroll
        for (int n = 0; n < 4; ++n) acc[m][n] = (f32x4){0.f, 0.f, 0.f, 0.f};

    for (int kt = 0; kt < K; kt += 64) {
#pragma unroll
        for (int j = 0; j < 4; ++j) {
            int slot = w * 4 + j;
            gld_lds16(A + (size_t)(bm + rs[j]) * K + kt + cs[j] * 8, As + slot * 512);
            gld_lds16(W + (size_t)(bn + rs[j]) * K + kt + cs[j] * 8, Bs + slot * 512);
        }
        __syncthreads();
#pragma unroll
        for (int kk = 0; kk < 2; ++kk) {
            bf16x8 af[4], bfr[4];
#pragma unroll
            for (int m = 0; m < 4; ++m) {
                int r = wr * 64 + m * 16 + r15;
                int c = (kk * 4 + g4) ^ (r & 7);
                af[m] = *(const bf16x8*)(As + r * 64 + c * 8);
            }
#pragma unroll
            for (int n = 0; n < 4; ++n) {
                int r = wc * 64 + n * 16 + r15;
                int c = (kk * 4 + g4) ^ (r & 7);
                bfr[n] = *(const bf16x8*)(Bs + r * 64 + c * 8);
            }
#pragma unroll
            for (int m = 0; m < 4; ++m)
#pragma unroll
                for (int n = 0; n < 4; ++n)
                    acc[m][n] = __builtin_amdgcn_mfma_f32_16x16x32_bf16(af[m], bfr[n], acc[m][n], 0, 0, 0);
        }
        __syncthreads();
    }

    const int row0 = bm + wr * 64 + g4 * 4;
    const int col0 = bn + wc * 64 + r15;
#pragma unroll
    for (int n = 0; n < 4; ++n) {
        const int col = col0 + n * 16;
        const float bv = bias[col];
#pragma unroll
        for (int m = 0; m < 4; ++m) {
#pragma unroll
            for (int j = 0; j < 4; ++j) {
                const int row = row0 + m * 16 + j;
                size_t off = (size_t)row * N + col;
                float v = acc[m][n][j] + bv;
                if (HAS_RES) v += (float)res[off];
                if (RELU) v = fmaxf(v, 0.f);
                outb[off] = (bf16_t)v;
            }
        }
    }
}

// ---------------- flash attention (bf16 MFMA), no-max softmax, 8 waves / 128 q-rows ----------
// (512,3): 3 blocks/CU (VGPR 48 <= 85 cap, LDS 3x36KB <= 160KB) — hides barrier drains.
// V^T staging split across all 512 threads (was 256 + idle half).
__global__ __launch_bounds__(512, 3) void attn_k(const bf16_t* __restrict__ qkv, bf16_t* __restrict__ out) {
    const int bid  = xcd_swz(blockIdx.x, gridDim.x);
    const int qblk = bid & 3;
    const int h    = (bid >> 2) & 7;
    const int bb   = bid >> 5;
    const int tid  = threadIdx.x;
    const int lane = tid & 63;
    const int w    = tid >> 6;
    const int r15  = lane & 15;
    const int g4   = lane >> 4;

    __shared__ __align__(16) bf16_t Ks[64 * 64];
    __shared__ __align__(16) bf16_t VT[64 * 72];
    __shared__ __align__(16) bf16_t Ps[8][16 * 72];

    const size_t base = (size_t)bb * Sd * 1536;
    const int q0 = qblk * 128 + w * 16;

    bf16x8 qf[2];
    {
        const int qr = q0 + r15;
#pragma unroll
        for (int kk = 0; kk < 2; ++kk)
            qf[kk] = *(const bf16x8*)(qkv + base + (size_t)qr * 1536 + h * 64 + kk * 32 + g4 * 8);
    }

    f32x4 oacc[4];
#pragma unroll
    for (int dg = 0; dg < 4; ++dg) oacc[dg] = (f32x4){0.f, 0.f, 0.f, 0.f};
    float lrun[4] = {0.f, 0.f, 0.f, 0.f};

    for (int kv0 = 0; kv0 < Sd; kv0 += 64) {
        __syncthreads();
        // K staging via global_load_lds (linear dest + inverse-swizzled source, G21)
        {
            const int r = tid >> 3, c = tid & 7;
            const int cl = c ^ (r & 7);
            gld_lds16(qkv + base + (size_t)(kv0 + r) * 1536 + 512 + h * 64 + cl * 8,
                      Ks + (w * 64) * 8);
        }
        // V^T staging: 256 pair-chunks split across 512 threads (2 threads per chunk,
        // each packs 4 of the 8 b32 words). uint2 (8B) loads, coalesced.
        {
            const int item = tid >> 1, half = tid & 1;      // item 0..255
            const int r2 = item >> 3, c = item & 7;         // kv pair (2r2,2r2+1), d-chunk c
            const bf16_t* vc = qkv + base + (size_t)(kv0 + 2 * r2) * 1536 + 1024 + h * 64
                               + c * 8 + half * 4;
            uint2 va = *(const uint2*)vc;
            uint2 vb = *(const uint2*)(vc + 1536);
            const u16* pa = (const u16*)&va;
            const u16* pb = (const u16*)&vb;
            const int rx = (2 * r2) ^ (c << 3);             // kv XOR-swizzle (bit0 free)
#pragma unroll
            for (int e = 0; e < 4; ++e) {
                u32 wv = (u32)pa[e] | ((u32)pb[e] << 16);
                *(u32*)(VT + (c * 8 + half * 4 + e) * 72 + rx) = wv;
            }
        }
        __syncthreads();

        f32x4 sreg[4];
#pragma unroll
        for (int cg = 0; cg < 4; ++cg) {
            f32x4 a = (f32x4){0.f, 0.f, 0.f, 0.f};
#pragma unroll
            for (int kk = 0; kk < 2; ++kk) {
                int rk = cg * 16 + r15;
                int ck = (kk * 4 + g4) ^ (rk & 7);
                bf16x8 kf = *(const bf16x8*)(Ks + rk * 64 + ck * 8);
                a = __builtin_amdgcn_mfma_f32_16x16x32_bf16(qf[kk], kf, a, 0, 0, 0);
            }
            sreg[cg] = a * 0.125f;
        }

        float rsum[4] = {0.f, 0.f, 0.f, 0.f};
#pragma unroll
        for (int cg = 0; cg < 4; ++cg)
#pragma unroll
            for (int j = 0; j < 4; ++j) {
                float pv = __expf(sreg[cg][j]);
                sreg[cg][j] = pv;
                rsum[j] += pv;
            }
#pragma unroll
        for (int j = 0; j < 4; ++j) {
#pragma unroll
            for (int o = 1; o < 16; o <<= 1) rsum[j] += __shfl_xor(rsum[j], o);
            lrun[j] += rsum[j];
        }

#pragma unroll
        for (int cg = 0; cg < 4; ++cg)
#pragma unroll
            for (int j = 0; j < 4; ++j)
                Ps[w][(g4 * 4 + j) * 72 + cg * 16 + r15] = (bf16_t)sreg[cg][j];

        bf16x8 pf[2];
#pragma unroll
        for (int kk = 0; kk < 2; ++kk)
            pf[kk] = *(const bf16x8*)(&Ps[w][0] + r15 * 72 + kk * 32 + g4 * 8);

#pragma unroll
        for (int dg = 0; dg < 4; ++dg)
#pragma unroll
            for (int kk = 0; kk < 2; ++kk) {
                const int d = dg * 16 + r15;
                const int kvx = (kk * 32 + g4 * 8) ^ (((d >> 3) & 7) << 3);
                bf16x8 vf = *(const bf16x8*)(VT + d * 72 + kvx);
                oacc[dg] = __builtin_amdgcn_mfma_f32_16x16x32_bf16(pf[kk], vf, oacc[dg], 0, 0, 0);
            }
    }

#pragma unroll
    for (int dg = 0; dg < 4; ++dg)
#pragma unroll
        for (int j = 0; j < 4; ++j) {
            int row = q0 + g4 * 4 + j;
            out[(size_t)(bb * Sd + row) * Dd + h * 64 + dg * 16 + r15] = (bf16_t)(oacc[dg][j] / lrun[j]);
        }
}

// ---------------- LayerNorm over D=512 (bf16 in -> bf16 out); wave per row ----------------
__global__ __launch_bounds__(256) void ln_k(const bf16_t* __restrict__ in, const float* __restrict__ gg,
                                            const float* __restrict__ bb, bf16_t* __restrict__ outb) {
    const int w = threadIdx.x >> 6, lane = threadIdx.x & 63;
    const size_t row = (size_t)blockIdx.x * 4 + w;
    const int col = lane * 8;
    bf16x8 xv = *(const bf16x8*)(in + row * 512 + col);
    float x[8];
#pragma unroll
    for (int i = 0; i < 8; ++i) x[i] = (float)xv[i];
    float s = 0.f, sq = 0.f;
#pragma unroll
    for (int i = 0; i < 8; ++i) { s += x[i]; sq += x[i] * x[i]; }
#pragma unroll
    for (int o = 1; o < 64; o <<= 1) { s += __shfl_xor(s, o); sq += __shfl_xor(sq, o); }
    const float mean = s * (1.f / 512.f);
    const float var  = sq * (1.f / 512.f) - mean * mean;
    const float rstd = rsqrtf(var + 1e-5f);
    const float4 g0 = *(const float4*)(gg + col), g1 = *(const float4*)(gg + col + 4);
    const float4 b0 = *(const float4*)(bb + col), b1 = *(const float4*)(bb + col + 4);
    const float g[8] = {g0.x, g0.y, g0.z, g0.w, g1.x, g1.y, g1.z, g1.w};
    const float b[8] = {b0.x, b0.y, b0.z, b0.w, b1.x, b1.y, b1.z, b1.w};
    bf16x8 ob;
#pragma unroll
    for (int i = 0; i < 8; ++i) ob[i] = (bf16_t)((x[i] - mean) * rstd * g[i] + b[i]);
    *(bf16x8*)(outb + row * 512 + col) = ob;
}

// ---------------- head: 4 projections of h=x[:,-1] (bf16 spine) -> d_out (fp32), z sampling ----
__global__ __launch_bounds__(256) void head_k(const bf16_t* __restrict__ xsp,
                                              const float* __restrict__ Wm, const float* __restrict__ bm,
                                              const float* __restrict__ Wlv, const float* __restrict__ blv,
                                              const float* __restrict__ Wsc, const float* __restrict__ bsc,
                                              const float* __restrict__ Wsh, const float* __restrict__ bsh,
                                              const float* __restrict__ pi, const float* __restrict__ eps,
                                              const float* __restrict__ u, const float* __restrict__ choice,
                                              float* __restrict__ outp, float* __restrict__ z) {
    const int b = blockIdx.x;
    const int tid = threadIdx.x;
    __shared__ __align__(16) float hl[512];
    __shared__ float dots[4][64];
    const bf16_t* h = xsp + (size_t)(b * Sd + (Sd - 1)) * Dd;
    for (int i = tid; i < 512; i += 256) hl[i] = (float)h[i];
    __syncthreads();
    const int head = tid >> 6, zi = tid & 63;
    const float* Wp = head == 0 ? Wm : head == 1 ? Wlv : head == 2 ? Wsc : Wsh;
    const float* bp = head == 0 ? bm : head == 1 ? blv : head == 2 ? bsc : bsh;
    const float4* w4 = (const float4*)(Wp + zi * 512);
    const float4* h4 = (const float4*)hl;
    float acc = 0.f;
    for (int k = 0; k < 128; ++k) {
        float4 x = h4[k], y = w4[k];
        acc += x.x * y.x + x.y * y.y + x.z * y.z + x.w * y.w;
    }
    acc += bp[zi];
    float outv = (head == 2) ? __expf(acc) : acc;
    dots[head][zi] = outv;
    outp[FUTd * Bd + head * (Bd * Zd) + b * Zd + zi] = outv;
    __syncthreads();
    if (tid < 64) {
        float mean = dots[0][tid], lv = dots[1][tid], sc = dots[2][tid], sh = dots[3][tid];
        float a0 = pi[0], a1 = pi[1];
        float mx = fmaxf(a0, a1);
        float e0 = __expf(a0 - mx), e1 = __expf(a1 - mx);
        float pi0 = e0 / (e0 + e1);
        float zg = mean + eps[b * 64 + tid] * __expf(0.5f * lv);
        float uu = u[b * 64 + tid];
        float zp = sc / sh * (powf(1.f - uu, -sh) - 1.f);
        z[b * 64 + tid] = (choice[b] < pi0) ? zg : zp;
    }
}

// ---------------- small fp32 GEMM for the MLP tail (fp32 out) ----------------
template<bool RELU>
__global__ void sgemm_k(const float* __restrict__ A, const float* __restrict__ W,
                        const float* __restrict__ bias, float* __restrict__ outf,
                        int M, int N, int K) {
    int idx = blockIdx.x * 256 + threadIdx.x;
    if (idx >= M * N) return;
    int row = idx / N, col = idx - row * N;
    const float4* a4 = (const float4*)(A + (size_t)row * K);
    const float4* w4 = (const float4*)(W + (size_t)col * K);
    float acc = 0.f;
    for (int k = 0; k < (K >> 2); ++k) {
        float4 x = a4[k], y = w4[k];
        acc += x.x * y.x + x.y * y.y + x.z * y.z + x.w * y.w;
    }
    acc += bias[col];
    if (RELU) acc = fmaxf(acc, 0.f);
    outf[idx] = acc;
}

extern "C" void kernel_launch(void* const* d_in, const int* in_sizes, int n_in,
                              void* d_out, int out_size, void* d_ws, size_t ws_size,
                              hipStream_t stream) {
    const float* X      = (const float*)d_in[0];
    const float* eps    = (const float*)d_in[1];
    const float* u      = (const float*)d_in[2];
    const float* choice = (const float*)d_in[3];
    const float* We     = (const float*)d_in[4];
    const float* be     = (const float*)d_in[5];
    const float* Wqkv   = (const float*)d_in[6];
    const float* bqkv   = (const float*)d_in[7];
    const float* Wo     = (const float*)d_in[8];
    const float* bo     = (const float*)d_in[9];
    const float* ln1g   = (const float*)d_in[10];
    const float* ln1b   = (const float*)d_in[11];
    const float* W1     = (const float*)d_in[12];
    const float* b1     = (const float*)d_in[13];
    const float* W2     = (const float*)d_in[14];
    const float* b2     = (const float*)d_in[15];
    const float* ln2g   = (const float*)d_in[16];
    const float* ln2b   = (const float*)d_in[17];
    const float* Wm     = (const float*)d_in[18];
    const float* bm     = (const float*)d_in[19];
    const float* Wlv    = (const float*)d_in[20];
    const float* blv    = (const float*)d_in[21];
    const float* Wsc    = (const float*)d_in[22];
    const float* bsc    = (const float*)d_in[23];
    const float* Wsh    = (const float*)d_in[24];
    const float* bsh    = (const float*)d_in[25];
    const float* pip    = (const float*)d_in[26];
    const float* Wfc1   = (const float*)d_in[27];
    const float* bfc1   = (const float*)d_in[28];
    const float* Wfc2   = (const float*)d_in[29];
    const float* bfc2   = (const float*)d_in[30];
    const float* Wout   = (const float*)d_in[31];
    const float* bout   = (const float*)d_in[32];
    const float* Wfin   = (const float*)d_in[33];
    const float* bfin   = (const float*)d_in[34];
    float* outp = (float*)d_out;

    const int BS = Bd * Sd;          // 32768 rows

    // fixed allocations (independent of chunking)
    const size_t fixed_bytes =
        ((size_t)Dd * 64 * 2 + 255 & ~(size_t)255) +
        ((size_t)Ld * 3 * Dd * Dd * 2 + 255 & ~(size_t)255) +
        ((size_t)Ld * Dd * Dd * 2 + 255 & ~(size_t)255) +
        ((size_t)Ld * FFd * Dd * 2 + 255 & ~(size_t)255) +
        ((size_t)Ld * Dd * FFd * 2 + 255 & ~(size_t)255) +
        ((size_t)BS * 64 * 2 + 255 & ~(size_t)255) +
        ((size_t)BS * Dd * 2 + 255 & ~(size_t)255) * 2 +
        ((size_t)Bd * Zd * 4 + 255 & ~(size_t)255) +
        ((size_t)Bd * 128 * 4 + 255 & ~(size_t)255) +
        ((size_t)Bd * 500 * 4 + 255 & ~(size_t)255) +
        ((size_t)Bd * FUTd * 4 + 255 & ~(size_t)255) + 4096;
    int BSC = BS;
    while (BSC >= 4096 && fixed_bytes + (size_t)BSC * FFd * 2 > ws_size) BSC >>= 1;
    const int nch = BS / BSC;

    char* p = (char*)d_ws;
    auto alloc = [&](size_t bytes) { char* r = p; p += (bytes + 255) & ~(size_t)255; return r; };
    bf16_t* We_b   = (bf16_t*)alloc((size_t)Dd * 64 * 2);
    bf16_t* Wqkv_b = (bf16_t*)alloc((size_t)Ld * 3 * Dd * Dd * 2);
    bf16_t* Wo_b   = (bf16_t*)alloc((size_t)Ld * Dd * Dd * 2);
    bf16_t* W1_b   = (bf16_t*)alloc((size_t)Ld * FFd * Dd * 2);
    bf16_t* W2_b   = (bf16_t*)alloc((size_t)Ld * Dd * FFd * 2);
    bf16_t* Xb     = (bf16_t*)alloc((size_t)BS * 64 * 2);
    bf16_t* xa     = (bf16_t*)alloc((size_t)BS * Dd * 2);
    bf16_t* xpre   = (bf16_t*)alloc((size_t)BS * Dd * 2);
    bf16_t* sbuf   = (bf16_t*)alloc((size_t)BSC * FFd * 2);
    float*  zbuf   = (float*)alloc((size_t)Bd * Zd * 4);
    float*  d1     = (float*)alloc((size_t)Bd * 128 * 4);
    float*  d2     = (float*)alloc((size_t)Bd * 500 * 4);
    float*  o3     = (float*)alloc((size_t)Bd * FUTd * 4);
    size_t needed = (size_t)(p - (char*)d_ws);
    if (ws_size < needed) return;

    auto cg = [](int n4) { return (n4 + 255) / 256; };
    cvt_k<<<cg(Dd * 64 / 4), 256, 0, stream>>>(We, We_b, Dd * 64 / 4);
    cvt_k<<<cg(Ld * 3 * Dd * Dd / 4), 256, 0, stream>>>(Wqkv, Wqkv_b, Ld * 3 * Dd * Dd / 4);
    cvt_k<<<cg(Ld * Dd * Dd / 4), 256, 0, stream>>>(Wo, Wo_b, Ld * Dd * Dd / 4);
    cvt_k<<<cg(Ld * FFd * Dd / 4), 256, 0, stream>>>(W1, W1_b, Ld * FFd * Dd / 4);
    cvt_k<<<cg(Ld * Dd * FFd / 4), 256, 0, stream>>>(W2, W2_b, Ld * Dd * FFd / 4);
    cvt_k<<<cg(BS * 64 / 4), 256, 0, stream>>>(X, Xb, BS * 64 / 4);

    // embed: xa = X @ We^T + be (bf16)
    gemm_k<false, false><<<dim3(Dd / 128, BS / 128), 256, 0, stream>>>(
        Xb, We_b, be, nullptr, xa, BS, Dd, 64);

    bf16_t* attno = sbuf + (size_t)BSC * 1536;

    for (int l = 0; l < Ld; ++l) {
        for (int hb = 0; hb < nch; ++hb) {
            bf16_t* xa_h   = xa   + (size_t)hb * BSC * Dd;
            bf16_t* xpre_h = xpre + (size_t)hb * BSC * Dd;
            gemm_k<false, false><<<dim3(3 * Dd / 128, BSC / 128), 256, 0, stream>>>(
                xa_h, Wqkv_b + (size_t)l * 3 * Dd * Dd, bqkv + (size_t)l * 3 * Dd, nullptr,
                sbuf, BSC, 3 * Dd, Dd);
            attn_k<<<(BSC / Sd) * Hd * (Sd / 128), 512, 0, stream>>>(sbuf, attno);
            gemm_k<false, true><<<dim3(Dd / 128, BSC / 128), 256, 0, stream>>>(
                attno, Wo_b + (size_t)l * Dd * Dd, bo + (size_t)l * Dd, xa_h,
                xpre_h, BSC, Dd, Dd);
        }
        ln_k<<<BS / 4, 256, 0, stream>>>(xpre, ln1g + (size_t)l * Dd, ln1b + (size_t)l * Dd, xa);
        for (int hb = 0; hb < nch; ++hb) {
            bf16_t* xa_h   = xa   + (size_t)hb * BSC * Dd;
            bf16_t* xpre_h = xpre + (size_t)hb * BSC * Dd;
            gemm_k<true, false><<<dim3(FFd / 128, BSC / 128), 256, 0, stream>>>(
                xa_h, W1_b + (size_t)l * FFd * Dd, b1 + (size_t)l * FFd, nullptr,
                sbuf, BSC, FFd, Dd);
            gemm_k<false, true><<<dim3(Dd / 128, BSC / 128), 256, 0, stream>>>(
                sbuf, W2_b + (size_t)l * Dd * FFd, b2 + (size_t)l * Dd, xa_h,
                xpre_h, BSC, Dd, FFd);
        }
        ln_k<<<BS / 4, 256, 0, stream>>>(xpre, ln2g + (size_t)l * Dd, ln2b + (size_t)l * Dd, xa);
    }

    head_k<<<Bd, 256, 0, stream>>>(xa, Wm, bm, Wlv, blv, Wsc, bsc, Wsh, bsh,
                                   pip, eps, u, choice, outp, zbuf);
    sgemm_k<true ><<<(Bd * 128 + 255) / 256, 256, 0, stream>>>(zbuf, Wfc1, bfc1, d1, Bd, 128, Zd);
    sgemm_k<true ><<<(Bd * 500 + 255) / 256, 256, 0, stream>>>(d1, Wfc2, bfc2, d2, Bd, 500, 128);
    sgemm_k<false><<<(Bd * FUTd + 255) / 256, 256, 0, stream>>>(d2, Wout, bout, o3, Bd, FUTd, 500);
    sgemm_k<false><<<(Bd * FUTd + 255) / 256, 256, 0, stream>>>(o3, Wfin, bfin, outp, Bd, FUTd, FUTd);
}

// Round 20
// 1596.561 us; speedup vs baseline: 1.2545x; 1.0436x over previous
//
#include <hip/hip_runtime.h>
#include <hip/hip_bf16.h>
#include <stdint.h>

typedef __bf16 bf16_t;
typedef __bf16 bf16x8 __attribute__((ext_vector_type(8)));
typedef __bf16 bf16x4 __attribute__((ext_vector_type(4)));
typedef float f32x4 __attribute__((ext_vector_type(4)));
typedef unsigned int u32;
typedef unsigned short u16;

static constexpr int Bd = 64, Sd = 512, Dd = 512, Hd = 8, Ld = 4, FFd = 2048, Zd = 64, FUTd = 96;

// ---------------- bijective XCD-aware block swizzle (T1, m204 form) ----------------
__device__ __forceinline__ int xcd_swz(int flat, int nwg) {
    int q = nwg >> 3, r = nwg & 7;
    int xcd = flat & 7, idx = flat >> 3;
    return (xcd < r ? xcd * (q + 1) : r * (q + 1) + (xcd - r) * q) + idx;
}

// ---------------- async global->LDS (16B per lane, wave-uniform LDS base) ----------------
__device__ __forceinline__ void gld_lds16(const bf16_t* g, bf16_t* l) {
    __builtin_amdgcn_global_load_lds(
        (const __attribute__((address_space(1))) u32*)g,
        (__attribute__((address_space(3))) u32*)l, 16, 0, 0);
}

// ---------------- fp32 -> bf16 conversion (vectorized x4) ----------------
__global__ void cvt_k(const float* __restrict__ in, bf16_t* __restrict__ out, int n4) {
    int i = blockIdx.x * 256 + threadIdx.x;
    if (i >= n4) return;
    float4 v = ((const float4*)in)[i];
    bf16x4 o;
    o[0] = (bf16_t)v.x; o[1] = (bf16_t)v.y; o[2] = (bf16_t)v.z; o[3] = (bf16_t)v.w;
    ((bf16x4*)out)[i] = o;
}

// ---------------- main bf16 MFMA GEMM (128x128): C = A@W^T + bias [+res(bf16)] [relu] ----------
template<bool RELU, bool HAS_RES>
__global__ __launch_bounds__(256, 3) void gemm_k(
    const bf16_t* __restrict__ A, const bf16_t* __restrict__ W,
    const float* __restrict__ bias, const bf16_t* __restrict__ res,
    bf16_t* __restrict__ outb, int M, int N, int K)
{
    __shared__ __align__(16) bf16_t As[128 * 64];
    __shared__ __align__(16) bf16_t Bs[128 * 64];
    const int tid  = threadIdx.x;
    const int lane = tid & 63;
    const int w    = tid >> 6;
    const int wr   = w >> 1, wc = w & 1;
    const int nwg  = gridDim.x * gridDim.y;
    const int flat = xcd_swz(blockIdx.y * gridDim.x + blockIdx.x, nwg);
    const int bm   = (flat / gridDim.x) * 128;
    const int bn   = (flat % gridDim.x) * 128;
    const int r15  = lane & 15;
    const int g4   = lane >> 4;

    int rs[4], cs[4];
#pragma unroll
    for (int j = 0; j < 4; ++j) {
        int slot = w * 4 + j;
        int r = slot * 8 + (lane >> 3);
        rs[j] = r;
        cs[j] = (lane & 7) ^ (r & 7);
    }

    f32x4 acc[4][4];
#pragma unroll
    for (int m = 0; m < 4; ++m)
#pragma unroll
        for (int n = 0; n < 4; ++n) acc[m][n] = (f32x4){0.f, 0.f, 0.f, 0.f};

    for (int kt = 0; kt < K; kt += 64) {
#pragma unroll
        for (int j = 0; j < 4; ++j) {
            int slot = w * 4 + j;
            gld_lds16(A + (size_t)(bm + rs[j]) * K + kt + cs[j] * 8, As + slot * 512);
            gld_lds16(W + (size_t)(bn + rs[j]) * K + kt + cs[j] * 8, Bs + slot * 512);
        }
        __syncthreads();
#pragma unroll
        for (int kk = 0; kk < 2; ++kk) {
            bf16x8 af[4], bfr[4];
#pragma unroll
            for (int m = 0; m < 4; ++m) {
                int r = wr * 64 + m * 16 + r15;
                int c = (kk * 4 + g4) ^ (r & 7);
                af[m] = *(const bf16x8*)(As + r * 64 + c * 8);
            }
#pragma unroll
            for (int n = 0; n < 4; ++n) {
                int r = wc * 64 + n * 16 + r15;
                int c = (kk * 4 + g4) ^ (r & 7);
                bfr[n] = *(const bf16x8*)(Bs + r * 64 + c * 8);
            }
#pragma unroll
            for (int m = 0; m < 4; ++m)
#pragma unroll
                for (int n = 0; n < 4; ++n)
                    acc[m][n] = __builtin_amdgcn_mfma_f32_16x16x32_bf16(af[m], bfr[n], acc[m][n], 0, 0, 0);
        }
        __syncthreads();
    }

    const int row0 = bm + wr * 64 + g4 * 4;
    const int col0 = bn + wc * 64 + r15;
#pragma unroll
    for (int n = 0; n < 4; ++n) {
        const int col = col0 + n * 16;
        const float bv = bias[col];
#pragma unroll
        for (int m = 0; m < 4; ++m) {
#pragma unroll
            for (int j = 0; j < 4; ++j) {
                const int row = row0 + m * 16 + j;
                size_t off = (size_t)row * N + col;
                float v = acc[m][n][j] + bv;
                if (HAS_RES) v += (float)res[off];
                if (RELU) v = fmaxf(v, 0.f);
                outb[off] = (bf16_t)v;
            }
        }
    }
}

// ---------------- flash attention (bf16 MFMA), no-max softmax, 8 waves / 128 q-rows ----------
// Round-18 staging (best measured). VALU shaves: Q pre-scaled by 1/8 (exact bf16 exponent
// shift, kills 16 f32 mults/tile) and lrun reduce deferred to epilogue (kills 16
// shuffles/tile; exact — no-max softmax never rescales).
__global__ __launch_bounds__(512, 2) void attn_k(const bf16_t* __restrict__ qkv, bf16_t* __restrict__ out) {
    const int bid  = xcd_swz(blockIdx.x, gridDim.x);
    const int qblk = bid & 3;
    const int h    = (bid >> 2) & 7;
    const int bb   = bid >> 5;
    const int tid  = threadIdx.x;
    const int lane = tid & 63;
    const int w    = tid >> 6;
    const int r15  = lane & 15;
    const int g4   = lane >> 4;

    __shared__ __align__(16) bf16_t Ks[64 * 64];
    __shared__ __align__(16) bf16_t VT[64 * 72];
    __shared__ __align__(16) bf16_t Ps[8][16 * 72];

    const size_t base = (size_t)bb * Sd * 1536;
    const int q0 = qblk * 128 + w * 16;

    bf16x8 qf[2];
    {
        const int qr = q0 + r15;
#pragma unroll
        for (int kk = 0; kk < 2; ++kk) {
            bf16x8 qv = *(const bf16x8*)(qkv + base + (size_t)qr * 1536 + h * 64 + kk * 32 + g4 * 8);
#pragma unroll
            for (int e = 0; e < 8; ++e) qv[e] = (bf16_t)((float)qv[e] * 0.125f);  // exact: exp-3
            qf[kk] = qv;
        }
    }

    f32x4 oacc[4];
#pragma unroll
    for (int dg = 0; dg < 4; ++dg) oacc[dg] = (f32x4){0.f, 0.f, 0.f, 0.f};
    float lrun[4] = {0.f, 0.f, 0.f, 0.f};   // per-lane partial (16 cols); reduced at epilogue

    for (int kv0 = 0; kv0 < Sd; kv0 += 64) {
        __syncthreads();
        // K staging via global_load_lds (linear dest + inverse-swizzled source, G21)
        {
            const int r = tid >> 3, c = tid & 7;
            const int cl = c ^ (r & 7);
            gld_lds16(qkv + base + (size_t)(kv0 + r) * 1536 + 512 + h * 64 + cl * 8,
                      Ks + (w * 64) * 8);
        }
        // V^T staging: threads 0..255 own kv pair (2*r2, 2*r2+1) -> 8 packed b32 writes
        if (tid < 256) {
            const int r2 = tid >> 3, c = tid & 7;
            const bf16_t* vc = qkv + base + (size_t)(kv0 + 2 * r2) * 1536 + 1024 + h * 64 + c * 8;
            uint4 va = *(const uint4*)vc;
            uint4 vb = *(const uint4*)(vc + 1536);
            const u16* pa = (const u16*)&va;
            const u16* pb = (const u16*)&vb;
            const int rx = (2 * r2) ^ (c << 3);
#pragma unroll
            for (int e = 0; e < 8; ++e) {
                u32 wv = (u32)pa[e] | ((u32)pb[e] << 16);
                *(u32*)(VT + (c * 8 + e) * 72 + rx) = wv;
            }
        }
        __syncthreads();

        f32x4 sreg[4];
#pragma unroll
        for (int cg = 0; cg < 4; ++cg) {
            f32x4 a = (f32x4){0.f, 0.f, 0.f, 0.f};
#pragma unroll
            for (int kk = 0; kk < 2; ++kk) {
                int rk = cg * 16 + r15;
                int ck = (kk * 4 + g4) ^ (rk & 7);
                bf16x8 kf = *(const bf16x8*)(Ks + rk * 64 + ck * 8);
                a = __builtin_amdgcn_mfma_f32_16x16x32_bf16(qf[kk], kf, a, 0, 0, 0);
            }
            sreg[cg] = a;   // scale already folded into Q
        }

        // P = exp(S); accumulate per-lane partial row-sums only (reduce deferred)
#pragma unroll
        for (int cg = 0; cg < 4; ++cg)
#pragma unroll
            for (int j = 0; j < 4; ++j) {
                float pv = __expf(sreg[cg][j]);
                sreg[cg][j] = pv;
                lrun[j] += pv;
            }

        // P -> LDS (per-wave region), C-layout -> A-layout relabel
#pragma unroll
        for (int cg = 0; cg < 4; ++cg)
#pragma unroll
            for (int j = 0; j < 4; ++j)
                Ps[w][(g4 * 4 + j) * 72 + cg * 16 + r15] = (bf16_t)sreg[cg][j];

        bf16x8 pf[2];
#pragma unroll
        for (int kk = 0; kk < 2; ++kk)
            pf[kk] = *(const bf16x8*)(&Ps[w][0] + r15 * 72 + kk * 32 + g4 * 8);

        // O += P @ V
#pragma unroll
        for (int dg = 0; dg < 4; ++dg)
#pragma unroll
            for (int kk = 0; kk < 2; ++kk) {
                const int d = dg * 16 + r15;
                const int kvx = (kk * 32 + g4 * 8) ^ (((d >> 3) & 7) << 3);
                bf16x8 vf = *(const bf16x8*)(VT + d * 72 + kvx);
                oacc[dg] = __builtin_amdgcn_mfma_f32_16x16x32_bf16(pf[kk], vf, oacc[dg], 0, 0, 0);
            }
    }

    // single deferred 16-lane reduce of the row sums
#pragma unroll
    for (int j = 0; j < 4; ++j)
#pragma unroll
        for (int o = 1; o < 16; o <<= 1) lrun[j] += __shfl_xor(lrun[j], o);

#pragma unroll
    for (int dg = 0; dg < 4; ++dg)
#pragma unroll
        for (int j = 0; j < 4; ++j) {
            int row = q0 + g4 * 4 + j;
            out[(size_t)(bb * Sd + row) * Dd + h * 64 + dg * 16 + r15] = (bf16_t)(oacc[dg][j] / lrun[j]);
        }
}

// ---------------- LayerNorm over D=512 (bf16 in -> bf16 out); wave per row ----------------
__global__ __launch_bounds__(256) void ln_k(const bf16_t* __restrict__ in, const float* __restrict__ gg,
                                            const float* __restrict__ bb, bf16_t* __restrict__ outb) {
    const int w = threadIdx.x >> 6, lane = threadIdx.x & 63;
    const size_t row = (size_t)blockIdx.x * 4 + w;
    const int col = lane * 8;
    bf16x8 xv = *(const bf16x8*)(in + row * 512 + col);
    float x[8];
#pragma unroll
    for (int i = 0; i < 8; ++i) x[i] = (float)xv[i];
    float s = 0.f, sq = 0.f;
#pragma unroll
    for (int i = 0; i < 8; ++i) { s += x[i]; sq += x[i] * x[i]; }
#pragma unroll
    for (int o = 1; o < 64; o <<= 1) { s += __shfl_xor(s, o); sq += __shfl_xor(sq, o); }
    const float mean = s * (1.f / 512.f);
    const float var  = sq * (1.f / 512.f) - mean * mean;
    const float rstd = rsqrtf(var + 1e-5f);
    const float4 g0 = *(const float4*)(gg + col), g1 = *(const float4*)(gg + col + 4);
    const float4 b0 = *(const float4*)(bb + col), b1 = *(const float4*)(bb + col + 4);
    const float g[8] = {g0.x, g0.y, g0.z, g0.w, g1.x, g1.y, g1.z, g1.w};
    const float b[8] = {b0.x, b0.y, b0.z, b0.w, b1.x, b1.y, b1.z, b1.w};
    bf16x8 ob;
#pragma unroll
    for (int i = 0; i < 8; ++i) ob[i] = (bf16_t)((x[i] - mean) * rstd * g[i] + b[i]);
    *(bf16x8*)(outb + row * 512 + col) = ob;
}

// ---------------- head: 4 projections of h=x[:,-1] (bf16 spine) -> d_out (fp32), z sampling ----
__global__ __launch_bounds__(256) void head_k(const bf16_t* __restrict__ xsp,
                                              const float* __restrict__ Wm, const float* __restrict__ bm,
                                              const float* __restrict__ Wlv, const float* __restrict__ blv,
                                              const float* __restrict__ Wsc, const float* __restrict__ bsc,
                                              const float* __restrict__ Wsh, const float* __restrict__ bsh,
                                              const float* __restrict__ pi, const float* __restrict__ eps,
                                              const float* __restrict__ u, const float* __restrict__ choice,
                                              float* __restrict__ outp, float* __restrict__ z) {
    const int b = blockIdx.x;
    const int tid = threadIdx.x;
    __shared__ __align__(16) float hl[512];
    __shared__ float dots[4][64];
    const bf16_t* h = xsp + (size_t)(b * Sd + (Sd - 1)) * Dd;
    for (int i = tid; i < 512; i += 256) hl[i] = (float)h[i];
    __syncthreads();
    const int head = tid >> 6, zi = tid & 63;
    const float* Wp = head == 0 ? Wm : head == 1 ? Wlv : head == 2 ? Wsc : Wsh;
    const float* bp = head == 0 ? bm : head == 1 ? blv : head == 2 ? bsc : bsh;
    const float4* w4 = (const float4*)(Wp + zi * 512);
    const float4* h4 = (const float4*)hl;
    float acc = 0.f;
    for (int k = 0; k < 128; ++k) {
        float4 x = h4[k], y = w4[k];
        acc += x.x * y.x + x.y * y.y + x.z * y.z + x.w * y.w;
    }
    acc += bp[zi];
    float outv = (head == 2) ? __expf(acc) : acc;
    dots[head][zi] = outv;
    outp[FUTd * Bd + head * (Bd * Zd) + b * Zd + zi] = outv;
    __syncthreads();
    if (tid < 64) {
        float mean = dots[0][tid], lv = dots[1][tid], sc = dots[2][tid], sh = dots[3][tid];
        float a0 = pi[0], a1 = pi[1];
        float mx = fmaxf(a0, a1);
        float e0 = __expf(a0 - mx), e1 = __expf(a1 - mx);
        float pi0 = e0 / (e0 + e1);
        float zg = mean + eps[b * 64 + tid] * __expf(0.5f * lv);
        float uu = u[b * 64 + tid];
        float zp = sc / sh * (powf(1.f - uu, -sh) - 1.f);
        z[b * 64 + tid] = (choice[b] < pi0) ? zg : zp;
    }
}

// ---------------- small fp32 GEMM for the MLP tail (fp32 out) ----------------
template<bool RELU>
__global__ void sgemm_k(const float* __restrict__ A, const float* __restrict__ W,
                        const float* __restrict__ bias, float* __restrict__ outf,
                        int M, int N, int K) {
    int idx = blockIdx.x * 256 + threadIdx.x;
    if (idx >= M * N) return;
    int row = idx / N, col = idx - row * N;
    const float4* a4 = (const float4*)(A + (size_t)row * K);
    const float4* w4 = (const float4*)(W + (size_t)col * K);
    float acc = 0.f;
    for (int k = 0; k < (K >> 2); ++k) {
        float4 x = a4[k], y = w4[k];
        acc += x.x * y.x + x.y * y.y + x.z * y.z + x.w * y.w;
    }
    acc += bias[col];
    if (RELU) acc = fmaxf(acc, 0.f);
    outf[idx] = acc;
}

extern "C" void kernel_launch(void* const* d_in, const int* in_sizes, int n_in,
                              void* d_out, int out_size, void* d_ws, size_t ws_size,
                              hipStream_t stream) {
    const float* X      = (const float*)d_in[0];
    const float* eps    = (const float*)d_in[1];
    const float* u      = (const float*)d_in[2];
    const float* choice = (const float*)d_in[3];
    const float* We     = (const float*)d_in[4];
    const float* be     = (const float*)d_in[5];
    const float* Wqkv   = (const float*)d_in[6];
    const float* bqkv   = (const float*)d_in[7];
    const float* Wo     = (const float*)d_in[8];
    const float* bo     = (const float*)d_in[9];
    const float* ln1g   = (const float*)d_in[10];
    const float* ln1b   = (const float*)d_in[11];
    const float* W1     = (const float*)d_in[12];
    const float* b1     = (const float*)d_in[13];
    const float* W2     = (const float*)d_in[14];
    const float* b2     = (const float*)d_in[15];
    const float* ln2g   = (const float*)d_in[16];
    const float* ln2b   = (const float*)d_in[17];
    const float* Wm     = (const float*)d_in[18];
    const float* bm     = (const float*)d_in[19];
    const float* Wlv    = (const float*)d_in[20];
    const float* blv    = (const float*)d_in[21];
    const float* Wsc    = (const float*)d_in[22];
    const float* bsc    = (const float*)d_in[23];
    const float* Wsh    = (const float*)d_in[24];
    const float* bsh    = (const float*)d_in[25];
    const float* pip    = (const float*)d_in[26];
    const float* Wfc1   = (const float*)d_in[27];
    const float* bfc1   = (const float*)d_in[28];
    const float* Wfc2   = (const float*)d_in[29];
    const float* bfc2   = (const float*)d_in[30];
    const float* Wout   = (const float*)d_in[31];
    const float* bout   = (const float*)d_in[32];
    const float* Wfin   = (const float*)d_in[33];
    const float* bfin   = (const float*)d_in[34];
    float* outp = (float*)d_out;

    const int BS = Bd * Sd;          // 32768 rows

    const size_t fixed_bytes =
        ((size_t)Dd * 64 * 2 + 255 & ~(size_t)255) +
        ((size_t)Ld * 3 * Dd * Dd * 2 + 255 & ~(size_t)255) +
        ((size_t)Ld * Dd * Dd * 2 + 255 & ~(size_t)255) +
        ((size_t)Ld * FFd * Dd * 2 + 255 & ~(size_t)255) +
        ((size_t)Ld * Dd * FFd * 2 + 255 & ~(size_t)255) +
        ((size_t)BS * 64 * 2 + 255 & ~(size_t)255) +
        ((size_t)BS * Dd * 2 + 255 & ~(size_t)255) * 2 +
        ((size_t)Bd * Zd * 4 + 255 & ~(size_t)255) +
        ((size_t)Bd * 128 * 4 + 255 & ~(size_t)255) +
        ((size_t)Bd * 500 * 4 + 255 & ~(size_t)255) +
        ((size_t)Bd * FUTd * 4 + 255 & ~(size_t)255) + 4096;
    int BSC = BS;
    while (BSC >= 4096 && fixed_bytes + (size_t)BSC * FFd * 2 > ws_size) BSC >>= 1;
    const int nch = BS / BSC;

    char* p = (char*)d_ws;
    auto alloc = [&](size_t bytes) { char* r = p; p += (bytes + 255) & ~(size_t)255; return r; };
    bf16_t* We_b   = (bf16_t*)alloc((size_t)Dd * 64 * 2);
    bf16_t* Wqkv_b = (bf16_t*)alloc((size_t)Ld * 3 * Dd * Dd * 2);
    bf16_t* Wo_b   = (bf16_t*)alloc((size_t)Ld * Dd * Dd * 2);
    bf16_t* W1_b   = (bf16_t*)alloc((size_t)Ld * FFd * Dd * 2);
    bf16_t* W2_b   = (bf16_t*)alloc((size_t)Ld * Dd * FFd * 2);
    bf16_t* Xb     = (bf16_t*)alloc((size_t)BS * 64 * 2);
    bf16_t* xa     = (bf16_t*)alloc((size_t)BS * Dd * 2);
    bf16_t* xpre   = (bf16_t*)alloc((size_t)BS * Dd * 2);
    bf16_t* sbuf   = (bf16_t*)alloc((size_t)BSC * FFd * 2);
    float*  zbuf   = (float*)alloc((size_t)Bd * Zd * 4);
    float*  d1     = (float*)alloc((size_t)Bd * 128 * 4);
    float*  d2     = (float*)alloc((size_t)Bd * 500 * 4);
    float*  o3     = (float*)alloc((size_t)Bd * FUTd * 4);
    size_t needed = (size_t)(p - (char*)d_ws);
    if (ws_size < needed) return;

    auto cg = [](int n4) { return (n4 + 255) / 256; };
    cvt_k<<<cg(Dd * 64 / 4), 256, 0, stream>>>(We, We_b, Dd * 64 / 4);
    cvt_k<<<cg(Ld * 3 * Dd * Dd / 4), 256, 0, stream>>>(Wqkv, Wqkv_b, Ld * 3 * Dd * Dd / 4);
    cvt_k<<<cg(Ld * Dd * Dd / 4), 256, 0, stream>>>(Wo, Wo_b, Ld * Dd * Dd / 4);
    cvt_k<<<cg(Ld * FFd * Dd / 4), 256, 0, stream>>>(W1, W1_b, Ld * FFd * Dd / 4);
    cvt_k<<<cg(Ld * Dd * FFd / 4), 256, 0, stream>>>(W2, W2_b, Ld * Dd * FFd / 4);
    cvt_k<<<cg(BS * 64 / 4), 256, 0, stream>>>(X, Xb, BS * 64 / 4);

    // embed: xa = X @ We^T + be (bf16)
    gemm_k<false, false><<<dim3(Dd / 128, BS / 128), 256, 0, stream>>>(
        Xb, We_b, be, nullptr, xa, BS, Dd, 64);

    bf16_t* attno = sbuf + (size_t)BSC * 1536;

    for (int l = 0; l < Ld; ++l) {
        for (int hb = 0; hb < nch; ++hb) {
            bf16_t* xa_h   = xa   + (size_t)hb * BSC * Dd;
            bf16_t* xpre_h = xpre + (size_t)hb * BSC * Dd;
            gemm_k<false, false><<<dim3(3 * Dd / 128, BSC / 128), 256, 0, stream>>>(
                xa_h, Wqkv_b + (size_t)l * 3 * Dd * Dd, bqkv + (size_t)l * 3 * Dd, nullptr,
                sbuf, BSC, 3 * Dd, Dd);
            attn_k<<<(BSC / Sd) * Hd * (Sd / 128), 512, 0, stream>>>(sbuf, attno);
            gemm_k<false, true><<<dim3(Dd / 128, BSC / 128), 256, 0, stream>>>(
                attno, Wo_b + (size_t)l * Dd * Dd, bo + (size_t)l * Dd, xa_h,
                xpre_h, BSC, Dd, Dd);
        }
        ln_k<<<BS / 4, 256, 0, stream>>>(xpre, ln1g + (size_t)l * Dd, ln1b + (size_t)l * Dd, xa);
        for (int hb = 0; hb < nch; ++hb) {
            bf16_t* xa_h   = xa   + (size_t)hb * BSC * Dd;
            bf16_t* xpre_h = xpre + (size_t)hb * BSC * Dd;
            gemm_k<true, false><<<dim3(FFd / 128, BSC / 128), 256, 0, stream>>>(
                xa_h, W1_b + (size_t)l * FFd * Dd, b1 + (size_t)l * FFd, nullptr,
                sbuf, BSC, FFd, Dd);
            gemm_k<false, true><<<dim3(Dd / 128, BSC / 128), 256, 0, stream>>>(
                sbuf, W2_b + (size_t)l * Dd * FFd, b2 + (size_t)l * Dd, xa_h,
                xpre_h, BSC, Dd, FFd);
        }
        ln_k<<<BS / 4, 256, 0, stream>>>(xpre, ln2g + (size_t)l * Dd, ln2b + (size_t)l * Dd, xa);
    }

    head_k<<<Bd, 256, 0, stream>>>(xa, Wm, bm, Wlv, blv, Wsc, bsc, Wsh, bsh,
                                   pip, eps, u, choice, outp, zbuf);
    sgemm_k<true ><<<(Bd * 128 + 255) / 256, 256, 0, stream>>>(zbuf, Wfc1, bfc1, d1, Bd, 128, Zd);
    sgemm_k<true ><<<(Bd * 500 + 255) / 256, 256, 0, stream>>>(d1, Wfc2, bfc2, d2, Bd, 500, 128);
    sgemm_k<false><<<(Bd * FUTd + 255) / 256, 256, 0, stream>>>(d2, Wout, bout, o3, Bd, FUTd, 500);
    sgemm_k<false><<<(Bd * FUTd + 255) / 256, 256, 0, stream>>>(o3, Wfin, bfin, outp, Bd, FUTd, FUTd);
}